// Round 10
// baseline (649.470 us; speedup 1.0000x reference)
//
#include <hip/hip_runtime.h>

#define BEVW 432
#define BEVH 496
#define NCELL (BEVW*BEVH)      // 214272
#define NVOX  40000
#define EPSB  1e-5f

typedef float f32x2 __attribute__((ext_vector_type(2)));
typedef float f32x4 __attribute__((ext_vector_type(4)));
typedef unsigned int u32x4 __attribute__((ext_vector_type(4)));
typedef short bf16x8 __attribute__((ext_vector_type(8)));   // 8 bf16 (guide-verified operand type)

// ---- repeat macros (token-pasted literal indices) ----
#define REP8_0(M)  M(0) M(1) M(2) M(3) M(4) M(5) M(6) M(7)
#define REP8_8(M)  M(8) M(9) M(10) M(11) M(12) M(13) M(14) M(15)
#define REP8_16(M) M(16) M(17) M(18) M(19) M(20) M(21) M(22) M(23)
#define REP8_24(M) M(24) M(25) M(26) M(27) M(28) M(29) M(30) M(31)
#define REP16_0(M)  REP8_0(M)  REP8_8(M)
#define REP32_0(M) REP16_0(M) REP8_16(M) REP8_24(M)

// ---------------- workspace layout (bytes) ----------------
// 0        : int nact (zeroed) | 256: int cnt[NCELL] (zeroed)
// 857600   : int list[NCELL*16]
// 14571008 : float voxelwise[NVOX*64]
// 24811008 : int act[NVOX]
// 24971008 : float x17g[NVOX*128]
// 45451008 : float fold[1168]
// 45455680 : ushort w4fh[4096]   (W4^T bf16-hi B-fragments)
// 45463872 : ushort w4fl[4096]   (W4^T bf16-lo B-fragments)

__device__ __forceinline__ float mishf(float y) {
    float e = __expf(fminf(y, 40.f));
    float n = e * (e + 2.f);
    return y * n * __builtin_amdgcn_rcpf(n + 2.f);
}

template <int CTRL>
__device__ __forceinline__ float dppmaxf(float a) {
    int p = __builtin_amdgcn_update_dpp(0, __float_as_int(a), CTRL, 0xF, 0xF, true);
    return fmaxf(a, __int_as_float(p));
}
#define WMAX32(a) { \
    a = dppmaxf<0xB1>(a); \
    a = dppmaxf<0x4E>(a); \
    a = dppmaxf<0x141>(a); \
    a = dppmaxf<0x140>(a); \
    a = fmaxf(a, __int_as_float(__builtin_amdgcn_ds_swizzle(__float_as_int(a), 0x401F))); }

__device__ __forceinline__ bf16x8 mkbf8(uint a, uint b, uint c, uint d) {
    u32x4 t = {a, b, c, d};
    return __builtin_bit_cast(bf16x8, t);
}

// split fp32 -> (hi bf16 | lo bf16 << 16), RNE both
__device__ __forceinline__ uint splitbf(float x) {
    uint ux = __float_as_uint(x);
    uint rh = (ux + 0x7FFFu + ((ux >> 16) & 1u)) & 0xFFFF0000u;
    float lof = x - __uint_as_float(rh);
    uint ul = __float_as_uint(lof);
    uint rl = (ul + 0x7FFFu + ((ul >> 16) & 1u)) >> 16;
    return (rh >> 16) | (rl << 16);
}

// fold layout: vfe1 s@0 t@8 | vfe2 s@16 t@48 | vfe3 s@80 t@144 | vfe4 s@208 t@272
// bfe3 s@336 t@464 | bfe1 s@592 t@848 | bfe2 s@1104 t@1136
__global__ __launch_bounds__(256) void setup_kernel(
    const float* __restrict__ vbn1, const float* __restrict__ vbn2,
    const float* __restrict__ vbn3, const float* __restrict__ vbn4,
    const float* __restrict__ bbn1, const float* __restrict__ bbn2,
    const float* __restrict__ bbn3, const float* __restrict__ W4,
    float* __restrict__ fold, ushort* __restrict__ w4fh, ushort* __restrict__ w4fl)
{
    int tid = threadIdx.x;
    if (tid < 8)  { float s = vbn1[tid]/sqrtf(vbn1[24+tid]+EPSB);  fold[tid]      = s; fold[8+tid]   = vbn1[8+tid]  - vbn1[16+tid]*s; }
    if (tid < 32) { float s = vbn2[tid]/sqrtf(vbn2[96+tid]+EPSB);  fold[16+tid]   = s; fold[48+tid]  = vbn2[32+tid] - vbn2[64+tid]*s; }
    if (tid < 64) { float s = vbn3[tid]/sqrtf(vbn3[192+tid]+EPSB); fold[80+tid]   = s; fold[144+tid] = vbn3[64+tid] - vbn3[128+tid]*s; }
    if (tid < 64) { float s = vbn4[tid]/sqrtf(vbn4[192+tid]+EPSB); fold[208+tid]  = s; fold[272+tid] = vbn4[64+tid] - vbn4[128+tid]*s; }
    if (tid < 128){ float s = bbn3[tid]/sqrtf(bbn3[384+tid]+EPSB); fold[336+tid]  = s; fold[464+tid] = bbn3[128+tid]- bbn3[256+tid]*s; }
    { int g = tid >> 4, q = tid & 15;
      const float* b = bbn1 + g*64;
      float s = b[q]/sqrtf(b[48+q]+EPSB);
      fold[592+tid] = s; fold[848+tid] = b[16+q] - b[32+q]*s; }
    if (tid < 32) { int g = tid >> 1, c = tid & 1;
      const float* b = bbn2 + g*8;
      float s = b[c]/sqrtf(b[6+c]+EPSB);
      fold[1104+tid] = s; fold[1136+tid] = b[2+c] - b[4+c]*s; }

    // W4^T B-fragments (B[k=o][n=q] = W4[q][o]), split bf16 hi/lo.
    // frag idx = ((kc*4 + nt)*64 + lane)*8 + j ; n = (lane&15)+16nt ; k = kc*32 + (lane>>4)*8 + j
    for (int i = tid; i < 4096; i += 256) {
        int j = i & 7, ln = (i >> 3) & 63, nt = (i >> 9) & 3, kc = i >> 11;
        int n = (ln & 15) + nt*16;
        int k = kc*32 + (ln >> 4)*8 + j;
        float val = W4[n*64 + k];
        uint ux = __float_as_uint(val);
        uint rh = (ux + 0x7FFFu + ((ux >> 16) & 1u)) & 0xFFFF0000u;
        float lof = val - __uint_as_float(rh);
        uint ul = __float_as_uint(lof);
        uint rl = (ul + 0x7FFFu + ((ul >> 16) & 1u)) >> 16;
        w4fh[i] = (ushort)(rh >> 16);
        w4fl[i] = (ushort)rl;
    }
}

// pair list: (pair index, scalar a, scalar b)
#define PAIRS(M) M(0,0,1) M(1,2,3) M(2,4,5) M(3,6,7) M(4,8,9) M(5,10,11) \
  M(6,12,13) M(7,14,15) M(8,16,17) M(9,18,19) M(10,20,21) M(11,22,23) \
  M(12,24,25) M(13,26,27) M(14,28,29) M(15,30,31)

#define MF3(D, AH, AL, BH, BL) \
    D = __builtin_amdgcn_mfma_f32_16x16x32_bf16(AL, BH, D, 0, 0, 0); \
    D = __builtin_amdgcn_mfma_f32_16x16x32_bf16(AH, BL, D, 0, 0, 0); \
    D = __builtin_amdgcn_mfma_f32_16x16x32_bf16(AH, BH, D, 0, 0, 0);

// ---------------- VFE: 8 voxels / 256-thr block; fe4 on matrix cores ----------------
// wave = 2 voxels (64 points). fe3 (VALU) streams x3 hi|lo u32 into stride-33 LDS;
// fe4 = 96 mfma_f32_16x16x32_bf16 (split-bf16 3-product). Residual+pool in C-layout.
// (256,4): VGPR=116 fits 4 waves/SIMD; LDS 34816*4 = 139 KB < 160 KB -> 4 blocks/CU.
// Round-9's (256,2) was the binding occupancy constraint (21.9%).
__global__ __launch_bounds__(256, 4) void vfe_kernel(
    const float* __restrict__ feat, const int* __restrict__ coors,
    const int* __restrict__ nvx,
    const float* __restrict__ W1, const float* __restrict__ W2,
    const float* __restrict__ W3,
    const ushort* __restrict__ w4fh, const ushort* __restrict__ w4fl,
    const float* __restrict__ fold,
    float* __restrict__ voxelwise, int* __restrict__ cnt,
    int* __restrict__ list, int* __restrict__ nact, int* __restrict__ act)
{
    __shared__ char ldsbuf[4*8704];   // per wave: 64x33 u32 (x3/x2resid) + 64 f32 aggL
    int tid = threadIdx.x;
    int lane = tid & 63;
    int wv = tid >> 6;
    int quad = lane >> 4;
    int v = blockIdx.x * 8 + (tid >> 5);      // per-lane voxel
    int vA = blockIdx.x * 8 + 2*wv;           // wave's first voxel
    int t = tid & 31;
    uint*  x3w  = (uint*)(ldsbuf + wv*8704);
    float* xw   = (float*)x3w;
    float* aggL = (float*)(ldsbuf + wv*8704 + 8448);

    const float* fp = feat + (v*32 + t)*8;
    float4 fa = *(const float4*)fp;
    float4 fb = *(const float4*)(fp+4);
    int numv = nvx[v];
    float maskf = (t < numv) ? 1.f : 0.f;

    // ---- fe1 (8->8) + pool ----
#define D1(o) float x1_##o; float m1_##o;
    REP8_0(D1)
#undef D1
#define FE1(o) { const float* w = W1 + (o)*8; \
    float ya = fa.x*w[0] + fa.y*w[1]; float yb = fa.z*w[2] + fa.w*w[3]; \
    float yc = fb.x*w[4] + fb.y*w[5]; float yd = fb.z*w[6] + fb.w*w[7]; \
    float yy = ((ya+yb)+(yc+yd)) * fold[(o)] + fold[8+(o)]; \
    x1_##o = mishf(yy); }
    REP8_0(FE1)
#undef FE1
#define P1(o) { float a = x1_##o; WMAX32(a); m1_##o = a; }
    REP8_0(P1)
#undef P1

    f32x2 x1p_0 = {x1_0,x1_1}, x1p_1 = {x1_2,x1_3}, x1p_2 = {x1_4,x1_5}, x1p_3 = {x1_6,x1_7};
    f32x2 m1p_0 = {m1_0,m1_1}, m1p_1 = {m1_2,m1_3}, m1p_2 = {m1_4,m1_5}, m1p_3 = {m1_6,m1_7};

    // ---- fe2 (16->32) + pool ----
#define D2(o) float x2_##o; float agg_##o;
    REP32_0(D2)
#undef D2
#define FE2(o) { const f32x2* wp = (const f32x2*)(W2 + (o)*16); \
    f32x2 sa = x1p_0*wp[0]; sa += x1p_1*wp[1]; \
    f32x2 sb = x1p_2*wp[2]; sb += x1p_3*wp[3]; \
    f32x2 sc = m1p_0*wp[4]; sc += m1p_1*wp[5]; \
    f32x2 sd = m1p_2*wp[6]; sd += m1p_3*wp[7]; \
    sa += sb; sc += sd; sa += sc; \
    float yy = (sa.x + sa.y) * fold[16+(o)] + fold[48+(o)]; \
    x2_##o = mishf(yy); }
    REP32_0(FE2)
#undef FE2
#define P2(o) { float a = x2_##o; WMAX32(a); agg_##o = a; }
    REP32_0(P2)
#undef P2

#define PX(i,a,b) f32x2 x2p_##i = {x2_##a, x2_##b}; f32x2 aggp_##i = {agg_##a, agg_##b};
    PAIRS(PX)
#undef PX

    // ---- yagg: fe3 contribution of voxel-uniform aggregate half ----
    const f32x2* wap = (const f32x2*)(W3 + t*64 + 32);
    const f32x2* wbp = (const f32x2*)(W3 + (t+32)*64 + 32);
    f32x2 yp1 = {0.f,0.f}, yp2 = {0.f,0.f};
#define YG(i) yp1 += aggp_##i * wap[i]; yp2 += aggp_##i * wbp[i];
    REP16_0(YG)
#undef YG
    float yagg1 = yp1.x + yp1.y, yagg2 = yp2.x + yp2.y;

    f32x2 maskp = {maskf, maskf};
#define MSK(i) x2p_##i *= maskp; aggp_##i *= maskp;
    REP16_0(MSK)
#undef MSK

    // aggL: exact fp32 unmasked agg (lane t==0 is always valid -> its masked copy == unmasked)
    if (t == 0) {
        float* ag = aggL + (lane >> 5)*32;
#define AGW(i) ag[2*(i)] = aggp_##i.x; ag[2*(i)+1] = aggp_##i.y;
        REP16_0(AGW)
#undef AGW
    }

    int nA = __shfl(numv, 0);
    int nB = __shfl(numv, 32);

    // ---- fe4 accumulators (MFMA C tiles, 16 x f32x4) ----
#define DD(i) f32x4 d_##i = {0.f,0.f,0.f,0.f};
    REP16_0(DD)
#undef DD

    // ---- fe3 (VALU, streamed by 32-o chunk) + fe4 (MFMA) ----
    for (int kc = 0; kc < 2; kc++) {
        float ysrc = kc ? yagg2 : yagg1;
        for (int o = 0; o < 32; o++) {
            int og = kc*32 + o;
            const f32x2* wp = (const f32x2*)(W3 + og*64);
            f32x2 s0 = x2p_0*wp[0];  s0 += x2p_1*wp[1];  s0 += x2p_2*wp[2];  s0 += x2p_3*wp[3];
            f32x2 s1 = x2p_4*wp[4];  s1 += x2p_5*wp[5];  s1 += x2p_6*wp[6];  s1 += x2p_7*wp[7];
            f32x2 s2 = x2p_8*wp[8];  s2 += x2p_9*wp[9];  s2 += x2p_10*wp[10]; s2 += x2p_11*wp[11];
            f32x2 s3 = x2p_12*wp[12]; s3 += x2p_13*wp[13]; s3 += x2p_14*wp[14]; s3 += x2p_15*wp[15];
            s0 += s1; s2 += s3; s0 += s2;
            float ya = __shfl(ysrc, o, 32);
            float yy = (s0.x + s0.y) + maskf * ya;
            yy = yy * fold[80+og] + fold[144+og];
            x3w[lane*33 + o] = splitbf(mishf(yy));
        }
        __syncthreads();

        // B fragments for this kc (L1-hot global)
        const uint4* bh = (const uint4*)w4fh + (kc*4)*64 + lane;
        const uint4* bl = (const uint4*)w4fl + (kc*4)*64 + lane;
        uint4 h0 = bh[0], h1 = bh[64], h2 = bh[128], h3 = bh[192];
        uint4 l0 = bl[0], l1 = bl[64], l2 = bl[128], l3 = bl[192];
        bf16x8 Bh0 = mkbf8(h0.x,h0.y,h0.z,h0.w), Bh1 = mkbf8(h1.x,h1.y,h1.z,h1.w);
        bf16x8 Bh2 = mkbf8(h2.x,h2.y,h2.z,h2.w), Bh3 = mkbf8(h3.x,h3.y,h3.z,h3.w);
        bf16x8 Bl0 = mkbf8(l0.x,l0.y,l0.z,l0.w), Bl1 = mkbf8(l1.x,l1.y,l1.z,l1.w);
        bf16x8 Bl2 = mkbf8(l2.x,l2.y,l2.z,l2.w), Bl3 = mkbf8(l3.x,l3.y,l3.z,l3.w);

#define DOMT(mt, D0, D1, D2, D3) { \
    int aoff = ((lane & 15) + 16*(mt))*33 + quad*8; \
    uint u0 = x3w[aoff+0], u1 = x3w[aoff+1], u2 = x3w[aoff+2], u3 = x3w[aoff+3]; \
    uint u4 = x3w[aoff+4], u5 = x3w[aoff+5], u6 = x3w[aoff+6], u7 = x3w[aoff+7]; \
    bf16x8 Ah = mkbf8(__builtin_amdgcn_perm(u1,u0,0x05040100), __builtin_amdgcn_perm(u3,u2,0x05040100), \
                      __builtin_amdgcn_perm(u5,u4,0x05040100), __builtin_amdgcn_perm(u7,u6,0x05040100)); \
    bf16x8 Al = mkbf8(__builtin_amdgcn_perm(u1,u0,0x07060302), __builtin_amdgcn_perm(u3,u2,0x07060302), \
                      __builtin_amdgcn_perm(u5,u4,0x07060302), __builtin_amdgcn_perm(u7,u6,0x07060302)); \
    MF3(d_##D0, Ah, Al, Bh0, Bl0) MF3(d_##D1, Ah, Al, Bh1, Bl1) \
    MF3(d_##D2, Ah, Al, Bh2, Bl2) MF3(d_##D3, Ah, Al, Bh3, Bl3) }

        DOMT(0, 0, 1, 2, 3)
        DOMT(1, 4, 5, 6, 7)
        DOMT(2, 8, 9, 10, 11)
        DOMT(3, 12, 13, 14, 15)
#undef DOMT
        __syncthreads();   // before next chunk overwrites x3w
    }

    // ---- stage exact fp32 masked pointwise x2 for the residual (reuse x3w) ----
#define XWR(i) xw[lane*33 + 2*(i)] = x2p_##i.x; xw[lane*33 + 2*(i)+1] = x2p_##i.y;
    REP16_0(XWR)
#undef XWR
    __syncthreads();

    // ---- bn4 + mish + residual + pool, in C layout (col=lane&15+16nt, row=quad*4+r+16mt) ----
    int c0 = lane & 15;
    float s0f = fold[208+c0],    t0f = fold[272+c0];
    float s1f = fold[208+16+c0], t1f = fold[272+16+c0];
    float s2f = fold[208+32+c0], t2f = fold[272+32+c0];
    float s3f = fold[208+48+c0], t3f = fold[272+48+c0];
    float rA2 = aggL[c0],      rA3 = aggL[16+c0];
    float rB2 = aggL[32+c0],   rB3 = aggL[48+c0];
    float pA0=-3.4e38f, pA1=-3.4e38f, pA2=-3.4e38f, pA3=-3.4e38f;
    float pB0=-3.4e38f, pB1=-3.4e38f, pB2=-3.4e38f, pB3=-3.4e38f;

#define FTP(D, mt, nt, SS, TT, PV) { \
    int nv = ((mt) >> 1) ? nB : nA; \
    int rf = quad*4 + 16*(mt); \
    int rt = quad*4 + 16*((mt)&1); \
    int cb = c0 + 16*(nt); \
    float m0=(rt+0<nv)?1.f:0.f, m1=(rt+1<nv)?1.f:0.f, m2=(rt+2<nv)?1.f:0.f, m3=(rt+3<nv)?1.f:0.f; \
    float y0 = mishf(D.x*SS + TT)*m0 + xw[(rf+0)*33 + cb]; \
    float y1 = mishf(D.y*SS + TT)*m1 + xw[(rf+1)*33 + cb]; \
    float y2 = mishf(D.z*SS + TT)*m2 + xw[(rf+2)*33 + cb]; \
    float y3 = mishf(D.w*SS + TT)*m3 + xw[(rf+3)*33 + cb]; \
    PV = fmaxf(PV, fmaxf(fmaxf(y0,y1), fmaxf(y2,y3))); }

#define FTA(D, mt, nt, SS, TT, AG, PV) { \
    int nv = ((mt) >> 1) ? nB : nA; \
    int rt = quad*4 + 16*((mt)&1); \
    float m0=(rt+0<nv)?1.f:0.f, m1=(rt+1<nv)?1.f:0.f, m2=(rt+2<nv)?1.f:0.f, m3=(rt+3<nv)?1.f:0.f; \
    float y0 = (mishf(D.x*SS + TT) + AG)*m0; \
    float y1 = (mishf(D.y*SS + TT) + AG)*m1; \
    float y2 = (mishf(D.z*SS + TT) + AG)*m2; \
    float y3 = (mishf(D.w*SS + TT) + AG)*m3; \
    PV = fmaxf(PV, fmaxf(fmaxf(y0,y1), fmaxf(y2,y3))); }

    FTP(d_0, 0, 0, s0f, t0f, pA0)  FTP(d_1, 0, 1, s1f, t1f, pA1)
    FTA(d_2, 0, 2, s2f, t2f, rA2, pA2)  FTA(d_3, 0, 3, s3f, t3f, rA3, pA3)
    FTP(d_4, 1, 0, s0f, t0f, pA0)  FTP(d_5, 1, 1, s1f, t1f, pA1)
    FTA(d_6, 1, 2, s2f, t2f, rA2, pA2)  FTA(d_7, 1, 3, s3f, t3f, rA3, pA3)
    FTP(d_8, 2, 0, s0f, t0f, pB0)  FTP(d_9, 2, 1, s1f, t1f, pB1)
    FTA(d_10, 2, 2, s2f, t2f, rB2, pB2)  FTA(d_11, 2, 3, s3f, t3f, rB3, pB3)
    FTP(d_12, 3, 0, s0f, t0f, pB0)  FTP(d_13, 3, 1, s1f, t1f, pB1)
    FTA(d_14, 3, 2, s2f, t2f, rB2, pB2)  FTA(d_15, 3, 3, s3f, t3f, rB3, pB3)
#undef FTP
#undef FTA

#define RED(p) p = fmaxf(p, __shfl_xor(p, 16)); p = fmaxf(p, __shfl_xor(p, 32));
    RED(pA0) RED(pA1) RED(pA2) RED(pA3) RED(pB0) RED(pB1) RED(pB2) RED(pB3)
#undef RED

    if (quad == 0) {
        float* vwA = voxelwise + vA*64;
        vwA[c0] = pA0; vwA[c0+16] = pA1; vwA[c0+32] = pA2; vwA[c0+48] = pA3;
        float* vwB = voxelwise + (vA+1)*64;
        vwB[c0] = pB0; vwB[c0+16] = pB1; vwB[c0+32] = pB2; vwB[c0+48] = pB3;
    }

    if (t == 0) {
        int cell = coors[v*2] * BEVW + coors[v*2+1];
        int pos = atomicAdd(&cnt[cell], 1);
        if (pos < 16) list[cell*16 + pos] = v;
        if (pos == 0) { int k = atomicAdd(nact, 1); act[k] = cell; }
    }
}

// ---------------- BFE front: 1 wave = 1 cell; weights direct from L1 ----------------
__global__ __launch_bounds__(256) void bfe_front(
    const int* __restrict__ nact, const int* __restrict__ act,
    const int* __restrict__ cnt, const int* __restrict__ list,
    const float* __restrict__ voxelwise,
    const float* __restrict__ W1g, const float* __restrict__ W2g,
    const float* __restrict__ fold, float* __restrict__ x17g)
{
    int n_act = *nact;
    int aidx = blockIdx.x * 4 + (threadIdx.x >> 6);
    if (aidx >= n_act) return;

    int lane = threadIdx.x & 63;
    int g = lane >> 2, ii = lane & 3;
    int cell = act[aidx];
    int numv = min(cnt[cell], 16);

    int myidx = (lane < numv) ? list[cell*16 + lane] : (0x40000000 + lane);
    int rank = 0;
    for (int j = 0; j < numv; j++) { int vj = __shfl(myidx, j); rank += (vj < myidx) ? 1 : 0; }
    if (lane >= numv) rank = lane;
    int sorted = __builtin_amdgcn_ds_permute(rank << 2, myidx);

#define YD(q) float y_##q = 0.f;
    REP16_0(YD)
#undef YD
    for (int p = 0; p < numv; p++) {
        int sv = __shfl(sorted, p);
        float val = voxelwise[sv*64 + lane];
        const float* w = W1g + g*256 + p;
#define BF1(q) y_##q += val * w[(q)*16];
        REP16_0(BF1)
#undef BF1
    }
#define BN1(q) { float yy = y_##q * fold[592 + g*16 + (q)] + fold[848 + g*16 + (q)]; \
    yy = mishf(yy); y_##q = ((q) < numv) ? yy : 0.f; }
    REP16_0(BN1)
#undef BN1

    float z0 = 0.f, z1 = 0.f;
#define BF2(p) z0 += y_##p * W2g[g*32 + (p)]; z1 += y_##p * W2g[g*32 + 16 + (p)];
    REP16_0(BF2)
#undef BF2
    z0 = mishf(z0 * fold[1104 + g*2 + 0] + fold[1136 + g*2 + 0]);
    z1 = mishf(z1 * fold[1104 + g*2 + 1] + fold[1136 + g*2 + 1]);

    int k0 = ii*32 + g*2;
    *(float2*)(x17g + aidx*128 + k0) = make_float2(z0, z1);
}

// ---------------- bfe3 fused (x18 and x19): GEMM-shaped, XL reused (32 KB) ----------------
__global__ __launch_bounds__(512, 4) void bfe3_fused(
    const int* __restrict__ nactp, const int* __restrict__ act,
    const float* __restrict__ W3, const float* __restrict__ fold,
    const float* __restrict__ x17g, float* __restrict__ out)
{
    __shared__ float XL[64*128];   // float4-chunk XOR swizzle: chunk kc at kc^(c&31)
    int tid = threadIdx.x;
    int n_act = *nactp;
    int cb = blockIdx.x * 64;

    for (int i = tid; i < 64*32; i += 512) {
        int c = i >> 5, kc = i & 31;
        float4 val = (cb + c < n_act) ? ((const float4*)x17g)[(size_t)(cb+c)*32 + kc]
                                      : make_float4(0.f,0.f,0.f,0.f);
        ((float4*)XL)[c*32 + (kc ^ (c & 31))] = val;
    }
    __syncthreads();

    int wv = __builtin_amdgcn_readfirstlane(tid >> 6);
    int c  = tid & 63;
    int ob = wv * 16;
    int cswz = c & 31;
    const float4* xrow = (const float4*)XL + c*32;
    const float4* W4p = (const float4*)W3;

#define DECLB(q) f32x2 ap_##q = {0.f, 0.f};
#define ACCB(q) { const f32x2* wp_ = (const f32x2*)(W4p + (ob+(q))*32 + kc); \
    ap_##q += xv01 * wp_[0]; ap_##q += xv23 * wp_[1]; }
#define ACTB(q) float a_##q; { float yy = (ap_##q.x + ap_##q.y) * fold[336+ob+(q)] + fold[464+ob+(q)]; a_##q = mishf(yy); }
    {
        REP16_0(DECLB)
        for (int kc = 0; kc < 32; kc++) {
            float4 xv = xrow[kc ^ cswz];
            f32x2 xv01 = {xv.x, xv.y}, xv23 = {xv.z, xv.w};
            REP16_0(ACCB)
        }
        REP16_0(ACTB)
        __syncthreads();   // everyone done READING XL
        ((float4*)XL)[c*32 + ((wv*4 + 0) ^ cswz)] = make_float4(a_0,  a_1,  a_2,  a_3);
        ((float4*)XL)[c*32 + ((wv*4 + 1) ^ cswz)] = make_float4(a_4,  a_5,  a_6,  a_7);
        ((float4*)XL)[c*32 + ((wv*4 + 2) ^ cswz)] = make_float4(a_8,  a_9,  a_10, a_11);
        ((float4*)XL)[c*32 + ((wv*4 + 3) ^ cswz)] = make_float4(a_12, a_13, a_14, a_15);
    }
    __syncthreads();

    {
        bool active = (cb + c) < n_act;
        int cell = active ? act[cb + c] : 0;
        int hh = cell / BEVW;
        int ww = cell - hh * BEVW;
        float* op = out + (size_t)ob*NCELL + ww*BEVH + hh;
        const float4* yrow = (const float4*)XL + c*32;
        REP16_0(DECLB)
        for (int kc = 0; kc < 32; kc++) {
            float4 xv = yrow[kc ^ cswz];
            f32x2 xv01 = {xv.x, xv.y}, xv23 = {xv.z, xv.w};
            REP16_0(ACCB)
        }
        REP16_0(ACTB)
        if (active) {
#define STOR(q) op[(q)*NCELL] = a_##q;
            REP16_0(STOR)
#undef STOR
        }
    }
#undef DECLB
#undef ACCB
#undef ACTB
}

extern "C" void kernel_launch(void* const* d_in, const int* in_sizes, int n_in,
                              void* d_out, int out_size, void* d_ws, size_t ws_size,
                              hipStream_t stream) {
    const float* features = (const float*)d_in[0];
    const int*   coors    = (const int*)d_in[1];
    const int*   num_vox  = (const int*)d_in[2];
    const float* vfe1_W   = (const float*)d_in[3];
    const float* vfe1_bn  = (const float*)d_in[4];
    const float* vfe2_W   = (const float*)d_in[5];
    const float* vfe2_bn  = (const float*)d_in[6];
    const float* vfe3_W   = (const float*)d_in[7];
    const float* vfe3_bn  = (const float*)d_in[8];
    const float* vfe4_W   = (const float*)d_in[9];
    const float* vfe4_bn  = (const float*)d_in[10];
    const float* bfe1_W   = (const float*)d_in[11];
    const float* bfe1_bn  = (const float*)d_in[12];
    const float* bfe2_W   = (const float*)d_in[13];
    const float* bfe2_bn  = (const float*)d_in[14];
    const float* bfe3_W   = (const float*)d_in[15];
    const float* bfe3_bn  = (const float*)d_in[16];
    float* out = (float*)d_out;

    char* ws = (char*)d_ws;
    int*    nact      = (int*)ws;
    int*    cnt       = (int*)(ws + 256);
    int*    list      = (int*)(ws + 857600);
    float*  voxelwise = (float*)(ws + 14571008);
    int*    act       = (int*)(ws + 24811008);
    float*  x17g      = (float*)(ws + 24971008);
    float*  fold      = (float*)(ws + 45451008);
    ushort* w4fh      = (ushort*)(ws + 45455680);
    ushort* w4fl      = (ushort*)(ws + 45463872);

    (void)hipMemsetAsync(ws, 0, 857600, stream);
    (void)hipMemsetAsync(d_out, 0, (size_t)out_size * sizeof(float), stream);

    setup_kernel<<<1, 256, 0, stream>>>(vfe1_bn, vfe2_bn, vfe3_bn, vfe4_bn,
                                        bfe1_bn, bfe2_bn, bfe3_bn, vfe4_W,
                                        fold, w4fh, w4fl);
    vfe_kernel<<<NVOX/8, 256, 0, stream>>>(features, coors, num_vox,
                                           vfe1_W, vfe2_W, vfe3_W, w4fh, w4fl, fold,
                                           voxelwise, cnt, list, nact, act);
    bfe_front<<<NVOX/4, 256, 0, stream>>>(nact, act, cnt, list, voxelwise,
                                          bfe1_W, bfe2_W, fold, x17g);
    bfe3_fused<<<(NVOX+63)/64, 512, 0, stream>>>(nact, act, bfe3_W, fold, x17g, out);
}

// Round 11
// 591.157 us; speedup vs baseline: 1.0986x; 1.0986x over previous
//
#include <hip/hip_runtime.h>

#define BEVW 432
#define BEVH 496
#define NCELL (BEVW*BEVH)      // 214272
#define NVOX  40000
#define EPSB  1e-5f

typedef float f32x2 __attribute__((ext_vector_type(2)));
typedef float f32x4 __attribute__((ext_vector_type(4)));
typedef unsigned int u32x4 __attribute__((ext_vector_type(4)));
typedef short bf16x8 __attribute__((ext_vector_type(8)));   // 8 bf16 (guide-verified operand type)

// ---- repeat macros (token-pasted literal indices) ----
#define REP8_0(M)  M(0) M(1) M(2) M(3) M(4) M(5) M(6) M(7)
#define REP8_8(M)  M(8) M(9) M(10) M(11) M(12) M(13) M(14) M(15)
#define REP8_16(M) M(16) M(17) M(18) M(19) M(20) M(21) M(22) M(23)
#define REP8_24(M) M(24) M(25) M(26) M(27) M(28) M(29) M(30) M(31)
#define REP16_0(M)  REP8_0(M)  REP8_8(M)
#define REP32_0(M) REP16_0(M) REP8_16(M) REP8_24(M)

// ---------------- workspace layout (bytes) ----------------
// 0        : int nact (zeroed) | 256: int cnt[NCELL] (zeroed)
// 857600   : int list[NCELL*16]
// 14571008 : float voxelwise[NVOX*64]
// 24811008 : int act[NVOX]
// 24971008 : float x17g[NVOX*128]
// 45451008 : float fold[1168]
// 45455680 : ushort w4fh[4096]   (W4^T bf16-hi B-fragments)
// 45463872 : ushort w4fl[4096]   (W4^T bf16-lo B-fragments)

__device__ __forceinline__ float mishf(float y) {
    float e = __expf(fminf(y, 40.f));
    float n = e * (e + 2.f);
    return y * n * __builtin_amdgcn_rcpf(n + 2.f);
}

template <int CTRL>
__device__ __forceinline__ float dppmaxf(float a) {
    int p = __builtin_amdgcn_update_dpp(0, __float_as_int(a), CTRL, 0xF, 0xF, true);
    return fmaxf(a, __int_as_float(p));
}
#define WMAX32(a) { \
    a = dppmaxf<0xB1>(a); \
    a = dppmaxf<0x4E>(a); \
    a = dppmaxf<0x141>(a); \
    a = dppmaxf<0x140>(a); \
    a = fmaxf(a, __int_as_float(__builtin_amdgcn_ds_swizzle(__float_as_int(a), 0x401F))); }

__device__ __forceinline__ bf16x8 mkbf8(uint a, uint b, uint c, uint d) {
    u32x4 t = {a, b, c, d};
    return __builtin_bit_cast(bf16x8, t);
}

// split fp32 -> (hi bf16 | lo bf16 << 16), RNE both
__device__ __forceinline__ uint splitbf(float x) {
    uint ux = __float_as_uint(x);
    uint rh = (ux + 0x7FFFu + ((ux >> 16) & 1u)) & 0xFFFF0000u;
    float lof = x - __uint_as_float(rh);
    uint ul = __float_as_uint(lof);
    uint rl = (ul + 0x7FFFu + ((ul >> 16) & 1u)) >> 16;
    return (rh >> 16) | (rl << 16);
}

// fold layout: vfe1 s@0 t@8 | vfe2 s@16 t@48 | vfe3 s@80 t@144 | vfe4 s@208 t@272
// bfe3 s@336 t@464 | bfe1 s@592 t@848 | bfe2 s@1104 t@1136
__global__ __launch_bounds__(256) void setup_kernel(
    const float* __restrict__ vbn1, const float* __restrict__ vbn2,
    const float* __restrict__ vbn3, const float* __restrict__ vbn4,
    const float* __restrict__ bbn1, const float* __restrict__ bbn2,
    const float* __restrict__ bbn3, const float* __restrict__ W4,
    float* __restrict__ fold, ushort* __restrict__ w4fh, ushort* __restrict__ w4fl)
{
    int tid = threadIdx.x;
    if (tid < 8)  { float s = vbn1[tid]/sqrtf(vbn1[24+tid]+EPSB);  fold[tid]      = s; fold[8+tid]   = vbn1[8+tid]  - vbn1[16+tid]*s; }
    if (tid < 32) { float s = vbn2[tid]/sqrtf(vbn2[96+tid]+EPSB);  fold[16+tid]   = s; fold[48+tid]  = vbn2[32+tid] - vbn2[64+tid]*s; }
    if (tid < 64) { float s = vbn3[tid]/sqrtf(vbn3[192+tid]+EPSB); fold[80+tid]   = s; fold[144+tid] = vbn3[64+tid] - vbn3[128+tid]*s; }
    if (tid < 64) { float s = vbn4[tid]/sqrtf(vbn4[192+tid]+EPSB); fold[208+tid]  = s; fold[272+tid] = vbn4[64+tid] - vbn4[128+tid]*s; }
    if (tid < 128){ float s = bbn3[tid]/sqrtf(bbn3[384+tid]+EPSB); fold[336+tid]  = s; fold[464+tid] = bbn3[128+tid]- bbn3[256+tid]*s; }
    { int g = tid >> 4, q = tid & 15;
      const float* b = bbn1 + g*64;
      float s = b[q]/sqrtf(b[48+q]+EPSB);
      fold[592+tid] = s; fold[848+tid] = b[16+q] - b[32+q]*s; }
    if (tid < 32) { int g = tid >> 1, c = tid & 1;
      const float* b = bbn2 + g*8;
      float s = b[c]/sqrtf(b[6+c]+EPSB);
      fold[1104+tid] = s; fold[1136+tid] = b[2+c] - b[4+c]*s; }

    // W4^T B-fragments (B[k=o][n=q] = W4[q][o]), split bf16 hi/lo.
    // frag idx = ((kc*4 + nt)*64 + lane)*8 + j ; n = (lane&15)+16nt ; k = kc*32 + (lane>>4)*8 + j
    for (int i = tid; i < 4096; i += 256) {
        int j = i & 7, ln = (i >> 3) & 63, nt = (i >> 9) & 3, kc = i >> 11;
        int n = (ln & 15) + nt*16;
        int k = kc*32 + (ln >> 4)*8 + j;
        float val = W4[n*64 + k];
        uint ux = __float_as_uint(val);
        uint rh = (ux + 0x7FFFu + ((ux >> 16) & 1u)) & 0xFFFF0000u;
        float lof = val - __uint_as_float(rh);
        uint ul = __float_as_uint(lof);
        uint rl = (ul + 0x7FFFu + ((ul >> 16) & 1u)) >> 16;
        w4fh[i] = (ushort)(rh >> 16);
        w4fl[i] = (ushort)rl;
    }
}

// pair list: (pair index, scalar a, scalar b)
#define PAIRS(M) M(0,0,1) M(1,2,3) M(2,4,5) M(3,6,7) M(4,8,9) M(5,10,11) \
  M(6,12,13) M(7,14,15) M(8,16,17) M(9,18,19) M(10,20,21) M(11,22,23) \
  M(12,24,25) M(13,26,27) M(14,28,29) M(15,30,31)

#define MF3(D, AH, AL, BH, BL) \
    D = __builtin_amdgcn_mfma_f32_16x16x32_bf16(AL, BH, D, 0, 0, 0); \
    D = __builtin_amdgcn_mfma_f32_16x16x32_bf16(AH, BL, D, 0, 0, 0); \
    D = __builtin_amdgcn_mfma_f32_16x16x32_bf16(AH, BH, D, 0, 0, 0);

// ---------------- VFE: 8 voxels / 256-thr block; fe4 on matrix cores ----------------
// wave = 2 voxels (64 points). fe3 (VALU) streams x3 hi|lo u32 into stride-33 LDS;
// fe4 = 96 mfma_f32_16x16x32_bf16 (split-bf16 3-product). Residual+pool in C-layout.
// (256,3): unified VGPR+AGPR budget 170/wave. B-frags loaded per A-tile group
// (transient, L1-hot) instead of held (32 regs) so peak ~155 fits without spill.
// Round-10 lesson: (256,4) = 128-cap -> 585 MB scratch traffic; counter VGPR_Count
// excludes AGPRs (64 acc regs here).
__global__ __launch_bounds__(256, 3) void vfe_kernel(
    const float* __restrict__ feat, const int* __restrict__ coors,
    const int* __restrict__ nvx,
    const float* __restrict__ W1, const float* __restrict__ W2,
    const float* __restrict__ W3,
    const ushort* __restrict__ w4fh, const ushort* __restrict__ w4fl,
    const float* __restrict__ fold,
    float* __restrict__ voxelwise, int* __restrict__ cnt,
    int* __restrict__ list, int* __restrict__ nact, int* __restrict__ act)
{
    __shared__ char ldsbuf[4*8704];   // per wave: 64x33 u32 (x3/x2resid) + 64 f32 aggL
    int tid = threadIdx.x;
    int lane = tid & 63;
    int wv = tid >> 6;
    int quad = lane >> 4;
    int v = blockIdx.x * 8 + (tid >> 5);      // per-lane voxel
    int vA = blockIdx.x * 8 + 2*wv;           // wave's first voxel
    int t = tid & 31;
    uint*  x3w  = (uint*)(ldsbuf + wv*8704);
    float* xw   = (float*)x3w;
    float* aggL = (float*)(ldsbuf + wv*8704 + 8448);

    const float* fp = feat + (v*32 + t)*8;
    float4 fa = *(const float4*)fp;
    float4 fb = *(const float4*)(fp+4);
    int numv = nvx[v];
    float maskf = (t < numv) ? 1.f : 0.f;

    // ---- fe1 (8->8) + pool ----
#define D1(o) float x1_##o; float m1_##o;
    REP8_0(D1)
#undef D1
#define FE1(o) { const float* w = W1 + (o)*8; \
    float ya = fa.x*w[0] + fa.y*w[1]; float yb = fa.z*w[2] + fa.w*w[3]; \
    float yc = fb.x*w[4] + fb.y*w[5]; float yd = fb.z*w[6] + fb.w*w[7]; \
    float yy = ((ya+yb)+(yc+yd)) * fold[(o)] + fold[8+(o)]; \
    x1_##o = mishf(yy); }
    REP8_0(FE1)
#undef FE1
#define P1(o) { float a = x1_##o; WMAX32(a); m1_##o = a; }
    REP8_0(P1)
#undef P1

    f32x2 x1p_0 = {x1_0,x1_1}, x1p_1 = {x1_2,x1_3}, x1p_2 = {x1_4,x1_5}, x1p_3 = {x1_6,x1_7};
    f32x2 m1p_0 = {m1_0,m1_1}, m1p_1 = {m1_2,m1_3}, m1p_2 = {m1_4,m1_5}, m1p_3 = {m1_6,m1_7};

    // ---- fe2 (16->32) + pool ----
#define D2(o) float x2_##o; float agg_##o;
    REP32_0(D2)
#undef D2
#define FE2(o) { const f32x2* wp = (const f32x2*)(W2 + (o)*16); \
    f32x2 sa = x1p_0*wp[0]; sa += x1p_1*wp[1]; \
    f32x2 sb = x1p_2*wp[2]; sb += x1p_3*wp[3]; \
    f32x2 sc = m1p_0*wp[4]; sc += m1p_1*wp[5]; \
    f32x2 sd = m1p_2*wp[6]; sd += m1p_3*wp[7]; \
    sa += sb; sc += sd; sa += sc; \
    float yy = (sa.x + sa.y) * fold[16+(o)] + fold[48+(o)]; \
    x2_##o = mishf(yy); }
    REP32_0(FE2)
#undef FE2
#define P2(o) { float a = x2_##o; WMAX32(a); agg_##o = a; }
    REP32_0(P2)
#undef P2

#define PX(i,a,b) f32x2 x2p_##i = {x2_##a, x2_##b}; f32x2 aggp_##i = {agg_##a, agg_##b};
    PAIRS(PX)
#undef PX

    // ---- yagg: fe3 contribution of voxel-uniform aggregate half ----
    const f32x2* wap = (const f32x2*)(W3 + t*64 + 32);
    const f32x2* wbp = (const f32x2*)(W3 + (t+32)*64 + 32);
    f32x2 yp1 = {0.f,0.f}, yp2 = {0.f,0.f};
#define YG(i) yp1 += aggp_##i * wap[i]; yp2 += aggp_##i * wbp[i];
    REP16_0(YG)
#undef YG
    float yagg1 = yp1.x + yp1.y, yagg2 = yp2.x + yp2.y;

    f32x2 maskp = {maskf, maskf};
#define MSK(i) x2p_##i *= maskp; aggp_##i *= maskp;
    REP16_0(MSK)
#undef MSK

    // aggL: exact fp32 unmasked agg (lane t==0 is always valid -> its masked copy == unmasked)
    if (t == 0) {
        float* ag = aggL + (lane >> 5)*32;
#define AGW(i) ag[2*(i)] = aggp_##i.x; ag[2*(i)+1] = aggp_##i.y;
        REP16_0(AGW)
#undef AGW
    }

    int nA = __shfl(numv, 0);
    int nB = __shfl(numv, 32);

    // ---- fe4 accumulators (MFMA C tiles, 16 x f32x4) ----
#define DD(i) f32x4 d_##i = {0.f,0.f,0.f,0.f};
    REP16_0(DD)
#undef DD

    // ---- fe3 (VALU, streamed by 32-o chunk) + fe4 (MFMA) ----
    for (int kc = 0; kc < 2; kc++) {
        float ysrc = kc ? yagg2 : yagg1;
        for (int o = 0; o < 32; o++) {
            int og = kc*32 + o;
            const f32x2* wp = (const f32x2*)(W3 + og*64);
            f32x2 s0 = x2p_0*wp[0];  s0 += x2p_1*wp[1];  s0 += x2p_2*wp[2];  s0 += x2p_3*wp[3];
            f32x2 s1 = x2p_4*wp[4];  s1 += x2p_5*wp[5];  s1 += x2p_6*wp[6];  s1 += x2p_7*wp[7];
            f32x2 s2 = x2p_8*wp[8];  s2 += x2p_9*wp[9];  s2 += x2p_10*wp[10]; s2 += x2p_11*wp[11];
            f32x2 s3 = x2p_12*wp[12]; s3 += x2p_13*wp[13]; s3 += x2p_14*wp[14]; s3 += x2p_15*wp[15];
            s0 += s1; s2 += s3; s0 += s2;
            float ya = __shfl(ysrc, o, 32);
            float yy = (s0.x + s0.y) + maskf * ya;
            yy = yy * fold[80+og] + fold[144+og];
            x3w[lane*33 + o] = splitbf(mishf(yy));
        }
        __syncthreads();

        // B fragment base pointers for this kc (16 KB L1-hot table)
        const uint4* bh = (const uint4*)w4fh + (kc*4)*64 + lane;
        const uint4* bl = (const uint4*)w4fl + (kc*4)*64 + lane;

        // Per A-tile group: load A frags from LDS, stream B frags from L1
        // (transient regs -> peak pressure fits 3 waves/SIMD).
#define MFNT(D, nt) { \
    uint4 h = bh[(nt)*64]; uint4 l = bl[(nt)*64]; \
    bf16x8 Bh = mkbf8(h.x,h.y,h.z,h.w); bf16x8 Bl = mkbf8(l.x,l.y,l.z,l.w); \
    MF3(D, Ah, Al, Bh, Bl) }

#define DOMT(mt, D0, D1, D2, D3) { \
    int aoff = ((lane & 15) + 16*(mt))*33 + quad*8; \
    uint u0 = x3w[aoff+0], u1 = x3w[aoff+1], u2 = x3w[aoff+2], u3 = x3w[aoff+3]; \
    uint u4 = x3w[aoff+4], u5 = x3w[aoff+5], u6 = x3w[aoff+6], u7 = x3w[aoff+7]; \
    bf16x8 Ah = mkbf8(__builtin_amdgcn_perm(u1,u0,0x05040100), __builtin_amdgcn_perm(u3,u2,0x05040100), \
                      __builtin_amdgcn_perm(u5,u4,0x05040100), __builtin_amdgcn_perm(u7,u6,0x05040100)); \
    bf16x8 Al = mkbf8(__builtin_amdgcn_perm(u1,u0,0x07060302), __builtin_amdgcn_perm(u3,u2,0x07060302), \
                      __builtin_amdgcn_perm(u5,u4,0x07060302), __builtin_amdgcn_perm(u7,u6,0x07060302)); \
    MFNT(d_##D0, 0) MFNT(d_##D1, 1) MFNT(d_##D2, 2) MFNT(d_##D3, 3) }

        DOMT(0, 0, 1, 2, 3)
        DOMT(1, 4, 5, 6, 7)
        DOMT(2, 8, 9, 10, 11)
        DOMT(3, 12, 13, 14, 15)
#undef DOMT
#undef MFNT
        __syncthreads();   // before next chunk overwrites x3w
    }

    // ---- stage exact fp32 masked pointwise x2 for the residual (reuse x3w) ----
#define XWR(i) xw[lane*33 + 2*(i)] = x2p_##i.x; xw[lane*33 + 2*(i)+1] = x2p_##i.y;
    REP16_0(XWR)
#undef XWR
    __syncthreads();

    // ---- bn4 + mish + residual + pool, in C layout (col=lane&15+16nt, row=quad*4+r+16mt) ----
    int c0 = lane & 15;
    float s0f = fold[208+c0],    t0f = fold[272+c0];
    float s1f = fold[208+16+c0], t1f = fold[272+16+c0];
    float s2f = fold[208+32+c0], t2f = fold[272+32+c0];
    float s3f = fold[208+48+c0], t3f = fold[272+48+c0];
    float rA2 = aggL[c0],      rA3 = aggL[16+c0];
    float rB2 = aggL[32+c0],   rB3 = aggL[48+c0];
    float pA0=-3.4e38f, pA1=-3.4e38f, pA2=-3.4e38f, pA3=-3.4e38f;
    float pB0=-3.4e38f, pB1=-3.4e38f, pB2=-3.4e38f, pB3=-3.4e38f;

#define FTP(D, mt, nt, SS, TT, PV) { \
    int nv = ((mt) >> 1) ? nB : nA; \
    int rf = quad*4 + 16*(mt); \
    int rt = quad*4 + 16*((mt)&1); \
    int cb = c0 + 16*(nt); \
    float m0=(rt+0<nv)?1.f:0.f, m1=(rt+1<nv)?1.f:0.f, m2=(rt+2<nv)?1.f:0.f, m3=(rt+3<nv)?1.f:0.f; \
    float y0 = mishf(D.x*SS + TT)*m0 + xw[(rf+0)*33 + cb]; \
    float y1 = mishf(D.y*SS + TT)*m1 + xw[(rf+1)*33 + cb]; \
    float y2 = mishf(D.z*SS + TT)*m2 + xw[(rf+2)*33 + cb]; \
    float y3 = mishf(D.w*SS + TT)*m3 + xw[(rf+3)*33 + cb]; \
    PV = fmaxf(PV, fmaxf(fmaxf(y0,y1), fmaxf(y2,y3))); }

#define FTA(D, mt, nt, SS, TT, AG, PV) { \
    int nv = ((mt) >> 1) ? nB : nA; \
    int rt = quad*4 + 16*((mt)&1); \
    float m0=(rt+0<nv)?1.f:0.f, m1=(rt+1<nv)?1.f:0.f, m2=(rt+2<nv)?1.f:0.f, m3=(rt+3<nv)?1.f:0.f; \
    float y0 = (mishf(D.x*SS + TT) + AG)*m0; \
    float y1 = (mishf(D.y*SS + TT) + AG)*m1; \
    float y2 = (mishf(D.z*SS + TT) + AG)*m2; \
    float y3 = (mishf(D.w*SS + TT) + AG)*m3; \
    PV = fmaxf(PV, fmaxf(fmaxf(y0,y1), fmaxf(y2,y3))); }

    FTP(d_0, 0, 0, s0f, t0f, pA0)  FTP(d_1, 0, 1, s1f, t1f, pA1)
    FTA(d_2, 0, 2, s2f, t2f, rA2, pA2)  FTA(d_3, 0, 3, s3f, t3f, rA3, pA3)
    FTP(d_4, 1, 0, s0f, t0f, pA0)  FTP(d_5, 1, 1, s1f, t1f, pA1)
    FTA(d_6, 1, 2, s2f, t2f, rA2, pA2)  FTA(d_7, 1, 3, s3f, t3f, rA3, pA3)
    FTP(d_8, 2, 0, s0f, t0f, pB0)  FTP(d_9, 2, 1, s1f, t1f, pB1)
    FTA(d_10, 2, 2, s2f, t2f, rB2, pB2)  FTA(d_11, 2, 3, s3f, t3f, rB3, pB3)
    FTP(d_12, 3, 0, s0f, t0f, pB0)  FTP(d_13, 3, 1, s1f, t1f, pB1)
    FTA(d_14, 3, 2, s2f, t2f, rB2, pB2)  FTA(d_15, 3, 3, s3f, t3f, rB3, pB3)
#undef FTP
#undef FTA

#define RED(p) p = fmaxf(p, __shfl_xor(p, 16)); p = fmaxf(p, __shfl_xor(p, 32));
    RED(pA0) RED(pA1) RED(pA2) RED(pA3) RED(pB0) RED(pB1) RED(pB2) RED(pB3)
#undef RED

    if (quad == 0) {
        float* vwA = voxelwise + vA*64;
        vwA[c0] = pA0; vwA[c0+16] = pA1; vwA[c0+32] = pA2; vwA[c0+48] = pA3;
        float* vwB = voxelwise + (vA+1)*64;
        vwB[c0] = pB0; vwB[c0+16] = pB1; vwB[c0+32] = pB2; vwB[c0+48] = pB3;
    }

    if (t == 0) {
        int cell = coors[v*2] * BEVW + coors[v*2+1];
        int pos = atomicAdd(&cnt[cell], 1);
        if (pos < 16) list[cell*16 + pos] = v;
        if (pos == 0) { int k = atomicAdd(nact, 1); act[k] = cell; }
    }
}

// ---------------- BFE front: 1 wave = 1 cell; weights direct from L1 ----------------
__global__ __launch_bounds__(256) void bfe_front(
    const int* __restrict__ nact, const int* __restrict__ act,
    const int* __restrict__ cnt, const int* __restrict__ list,
    const float* __restrict__ voxelwise,
    const float* __restrict__ W1g, const float* __restrict__ W2g,
    const float* __restrict__ fold, float* __restrict__ x17g)
{
    int n_act = *nact;
    int aidx = blockIdx.x * 4 + (threadIdx.x >> 6);
    if (aidx >= n_act) return;

    int lane = threadIdx.x & 63;
    int g = lane >> 2, ii = lane & 3;
    int cell = act[aidx];
    int numv = min(cnt[cell], 16);

    int myidx = (lane < numv) ? list[cell*16 + lane] : (0x40000000 + lane);
    int rank = 0;
    for (int j = 0; j < numv; j++) { int vj = __shfl(myidx, j); rank += (vj < myidx) ? 1 : 0; }
    if (lane >= numv) rank = lane;
    int sorted = __builtin_amdgcn_ds_permute(rank << 2, myidx);

#define YD(q) float y_##q = 0.f;
    REP16_0(YD)
#undef YD
    for (int p = 0; p < numv; p++) {
        int sv = __shfl(sorted, p);
        float val = voxelwise[sv*64 + lane];
        const float* w = W1g + g*256 + p;
#define BF1(q) y_##q += val * w[(q)*16];
        REP16_0(BF1)
#undef BF1
    }
#define BN1(q) { float yy = y_##q * fold[592 + g*16 + (q)] + fold[848 + g*16 + (q)]; \
    yy = mishf(yy); y_##q = ((q) < numv) ? yy : 0.f; }
    REP16_0(BN1)
#undef BN1

    float z0 = 0.f, z1 = 0.f;
#define BF2(p) z0 += y_##p * W2g[g*32 + (p)]; z1 += y_##p * W2g[g*32 + 16 + (p)];
    REP16_0(BF2)
#undef BF2
    z0 = mishf(z0 * fold[1104 + g*2 + 0] + fold[1136 + g*2 + 0]);
    z1 = mishf(z1 * fold[1104 + g*2 + 1] + fold[1136 + g*2 + 1]);

    int k0 = ii*32 + g*2;
    *(float2*)(x17g + aidx*128 + k0) = make_float2(z0, z1);
}

// ---------------- bfe3 fused (x18 and x19): GEMM-shaped, XL reused (32 KB) ----------------
__global__ __launch_bounds__(512, 4) void bfe3_fused(
    const int* __restrict__ nactp, const int* __restrict__ act,
    const float* __restrict__ W3, const float* __restrict__ fold,
    const float* __restrict__ x17g, float* __restrict__ out)
{
    __shared__ float XL[64*128];   // float4-chunk XOR swizzle: chunk kc at kc^(c&31)
    int tid = threadIdx.x;
    int n_act = *nactp;
    int cb = blockIdx.x * 64;

    for (int i = tid; i < 64*32; i += 512) {
        int c = i >> 5, kc = i & 31;
        float4 val = (cb + c < n_act) ? ((const float4*)x17g)[(size_t)(cb+c)*32 + kc]
                                      : make_float4(0.f,0.f,0.f,0.f);
        ((float4*)XL)[c*32 + (kc ^ (c & 31))] = val;
    }
    __syncthreads();

    int wv = __builtin_amdgcn_readfirstlane(tid >> 6);
    int c  = tid & 63;
    int ob = wv * 16;
    int cswz = c & 31;
    const float4* xrow = (const float4*)XL + c*32;
    const float4* W4p = (const float4*)W3;

#define DECLB(q) f32x2 ap_##q = {0.f, 0.f};
#define ACCB(q) { const f32x2* wp_ = (const f32x2*)(W4p + (ob+(q))*32 + kc); \
    ap_##q += xv01 * wp_[0]; ap_##q += xv23 * wp_[1]; }
#define ACTB(q) float a_##q; { float yy = (ap_##q.x + ap_##q.y) * fold[336+ob+(q)] + fold[464+ob+(q)]; a_##q = mishf(yy); }
    {
        REP16_0(DECLB)
        for (int kc = 0; kc < 32; kc++) {
            float4 xv = xrow[kc ^ cswz];
            f32x2 xv01 = {xv.x, xv.y}, xv23 = {xv.z, xv.w};
            REP16_0(ACCB)
        }
        REP16_0(ACTB)
        __syncthreads();   // everyone done READING XL
        ((float4*)XL)[c*32 + ((wv*4 + 0) ^ cswz)] = make_float4(a_0,  a_1,  a_2,  a_3);
        ((float4*)XL)[c*32 + ((wv*4 + 1) ^ cswz)] = make_float4(a_4,  a_5,  a_6,  a_7);
        ((float4*)XL)[c*32 + ((wv*4 + 2) ^ cswz)] = make_float4(a_8,  a_9,  a_10, a_11);
        ((float4*)XL)[c*32 + ((wv*4 + 3) ^ cswz)] = make_float4(a_12, a_13, a_14, a_15);
    }
    __syncthreads();

    {
        bool active = (cb + c) < n_act;
        int cell = active ? act[cb + c] : 0;
        int hh = cell / BEVW;
        int ww = cell - hh * BEVW;
        float* op = out + (size_t)ob*NCELL + ww*BEVH + hh;
        const float4* yrow = (const float4*)XL + c*32;
        REP16_0(DECLB)
        for (int kc = 0; kc < 32; kc++) {
            float4 xv = yrow[kc ^ cswz];
            f32x2 xv01 = {xv.x, xv.y}, xv23 = {xv.z, xv.w};
            REP16_0(ACCB)
        }
        REP16_0(ACTB)
        if (active) {
#define STOR(q) op[(q)*NCELL] = a_##q;
            REP16_0(STOR)
#undef STOR
        }
    }
#undef DECLB
#undef ACCB
#undef ACTB
}

extern "C" void kernel_launch(void* const* d_in, const int* in_sizes, int n_in,
                              void* d_out, int out_size, void* d_ws, size_t ws_size,
                              hipStream_t stream) {
    const float* features = (const float*)d_in[0];
    const int*   coors    = (const int*)d_in[1];
    const int*   num_vox  = (const int*)d_in[2];
    const float* vfe1_W   = (const float*)d_in[3];
    const float* vfe1_bn  = (const float*)d_in[4];
    const float* vfe2_W   = (const float*)d_in[5];
    const float* vfe2_bn  = (const float*)d_in[6];
    const float* vfe3_W   = (const float*)d_in[7];
    const float* vfe3_bn  = (const float*)d_in[8];
    const float* vfe4_W   = (const float*)d_in[9];
    const float* vfe4_bn  = (const float*)d_in[10];
    const float* bfe1_W   = (const float*)d_in[11];
    const float* bfe1_bn  = (const float*)d_in[12];
    const float* bfe2_W   = (const float*)d_in[13];
    const float* bfe2_bn  = (const float*)d_in[14];
    const float* bfe3_W   = (const float*)d_in[15];
    const float* bfe3_bn  = (const float*)d_in[16];
    float* out = (float*)d_out;

    char* ws = (char*)d_ws;
    int*    nact      = (int*)ws;
    int*    cnt       = (int*)(ws + 256);
    int*    list      = (int*)(ws + 857600);
    float*  voxelwise = (float*)(ws + 14571008);
    int*    act       = (int*)(ws + 24811008);
    float*  x17g      = (float*)(ws + 24971008);
    float*  fold      = (float*)(ws + 45451008);
    ushort* w4fh      = (ushort*)(ws + 45455680);
    ushort* w4fl      = (ushort*)(ws + 45463872);

    (void)hipMemsetAsync(ws, 0, 857600, stream);
    (void)hipMemsetAsync(d_out, 0, (size_t)out_size * sizeof(float), stream);

    setup_kernel<<<1, 256, 0, stream>>>(vfe1_bn, vfe2_bn, vfe3_bn, vfe4_bn,
                                        bfe1_bn, bfe2_bn, bfe3_bn, vfe4_W,
                                        fold, w4fh, w4fl);
    vfe_kernel<<<NVOX/8, 256, 0, stream>>>(features, coors, num_vox,
                                           vfe1_W, vfe2_W, vfe3_W, w4fh, w4fl, fold,
                                           voxelwise, cnt, list, nact, act);
    bfe_front<<<NVOX/4, 256, 0, stream>>>(nact, act, cnt, list, voxelwise,
                                          bfe1_W, bfe2_W, fold, x17g);
    bfe3_fused<<<(NVOX+63)/64, 512, 0, stream>>>(nact, act, bfe3_W, fold, x17g, out);
}

// Round 12
// 560.530 us; speedup vs baseline: 1.1587x; 1.0546x over previous
//
#include <hip/hip_runtime.h>

#define BEVW 432
#define BEVH 496
#define NCELL (BEVW*BEVH)      // 214272
#define NVOX  40000
#define EPSB  1e-5f

typedef float f32x2 __attribute__((ext_vector_type(2)));
typedef float f32x4 __attribute__((ext_vector_type(4)));
typedef unsigned int u32x4 __attribute__((ext_vector_type(4)));
typedef short bf16x8 __attribute__((ext_vector_type(8)));   // 8 bf16 (guide-verified operand type)

// ---- repeat macros (token-pasted literal indices) ----
#define REP8_0(M)  M(0) M(1) M(2) M(3) M(4) M(5) M(6) M(7)
#define REP8_8(M)  M(8) M(9) M(10) M(11) M(12) M(13) M(14) M(15)
#define REP8_16(M) M(16) M(17) M(18) M(19) M(20) M(21) M(22) M(23)
#define REP8_24(M) M(24) M(25) M(26) M(27) M(28) M(29) M(30) M(31)
#define REP16_0(M)  REP8_0(M)  REP8_8(M)
#define REP32_0(M) REP16_0(M) REP8_16(M) REP8_24(M)

// ---------------- workspace layout (bytes) ----------------
// 0        : int nact (zeroed) | 256: int cnt[NCELL] (zeroed)
// 857600   : int list[NCELL*16]
// 14571008 : float voxelwise[NVOX*64]
// 24811008 : int act[NVOX]
// 24971008 : float x17g[NVOX*128]   (holds x17, then x19 in-place)
// 45451008 : float fold[1168]
// 45455680 : ushort w4fh[4096]
// 45463872 : ushort w4fl[4096]
// 45472064 : int idx[NCELL]         (memset 0xFF -> -1)

__device__ __forceinline__ float mishf(float y) {
    float e = __expf(fminf(y, 40.f));
    float n = e * (e + 2.f);
    return y * n * __builtin_amdgcn_rcpf(n + 2.f);
}

template <int CTRL>
__device__ __forceinline__ float dppmaxf(float a) {
    int p = __builtin_amdgcn_update_dpp(0, __float_as_int(a), CTRL, 0xF, 0xF, true);
    return fmaxf(a, __int_as_float(p));
}
#define WMAX32(a) { \
    a = dppmaxf<0xB1>(a); \
    a = dppmaxf<0x4E>(a); \
    a = dppmaxf<0x141>(a); \
    a = dppmaxf<0x140>(a); \
    a = fmaxf(a, __int_as_float(__builtin_amdgcn_ds_swizzle(__float_as_int(a), 0x401F))); }

__device__ __forceinline__ bf16x8 mkbf8(uint a, uint b, uint c, uint d) {
    u32x4 t = {a, b, c, d};
    return __builtin_bit_cast(bf16x8, t);
}

// split fp32 -> (hi bf16 | lo bf16 << 16), RNE both
__device__ __forceinline__ uint splitbf(float x) {
    uint ux = __float_as_uint(x);
    uint rh = (ux + 0x7FFFu + ((ux >> 16) & 1u)) & 0xFFFF0000u;
    float lof = x - __uint_as_float(rh);
    uint ul = __float_as_uint(lof);
    uint rl = (ul + 0x7FFFu + ((ul >> 16) & 1u)) >> 16;
    return (rh >> 16) | (rl << 16);
}

// fold layout: vfe1 s@0 t@8 | vfe2 s@16 t@48 | vfe3 s@80 t@144 | vfe4 s@208 t@272
// bfe3 s@336 t@464 | bfe1 s@592 t@848 | bfe2 s@1104 t@1136
__global__ __launch_bounds__(256) void setup_kernel(
    const float* __restrict__ vbn1, const float* __restrict__ vbn2,
    const float* __restrict__ vbn3, const float* __restrict__ vbn4,
    const float* __restrict__ bbn1, const float* __restrict__ bbn2,
    const float* __restrict__ bbn3, const float* __restrict__ W4,
    float* __restrict__ fold, ushort* __restrict__ w4fh, ushort* __restrict__ w4fl)
{
    int tid = threadIdx.x;
    if (tid < 8)  { float s = vbn1[tid]/sqrtf(vbn1[24+tid]+EPSB);  fold[tid]      = s; fold[8+tid]   = vbn1[8+tid]  - vbn1[16+tid]*s; }
    if (tid < 32) { float s = vbn2[tid]/sqrtf(vbn2[96+tid]+EPSB);  fold[16+tid]   = s; fold[48+tid]  = vbn2[32+tid] - vbn2[64+tid]*s; }
    if (tid < 64) { float s = vbn3[tid]/sqrtf(vbn3[192+tid]+EPSB); fold[80+tid]   = s; fold[144+tid] = vbn3[64+tid] - vbn3[128+tid]*s; }
    if (tid < 64) { float s = vbn4[tid]/sqrtf(vbn4[192+tid]+EPSB); fold[208+tid]  = s; fold[272+tid] = vbn4[64+tid] - vbn4[128+tid]*s; }
    if (tid < 128){ float s = bbn3[tid]/sqrtf(bbn3[384+tid]+EPSB); fold[336+tid]  = s; fold[464+tid] = bbn3[128+tid]- bbn3[256+tid]*s; }
    { int g = tid >> 4, q = tid & 15;
      const float* b = bbn1 + g*64;
      float s = b[q]/sqrtf(b[48+q]+EPSB);
      fold[592+tid] = s; fold[848+tid] = b[16+q] - b[32+q]*s; }
    if (tid < 32) { int g = tid >> 1, c = tid & 1;
      const float* b = bbn2 + g*8;
      float s = b[c]/sqrtf(b[6+c]+EPSB);
      fold[1104+tid] = s; fold[1136+tid] = b[2+c] - b[4+c]*s; }

    // W4^T B-fragments (B[k=o][n=q] = W4[q][o]), split bf16 hi/lo.
    for (int i = tid; i < 4096; i += 256) {
        int j = i & 7, ln = (i >> 3) & 63, nt = (i >> 9) & 3, kc = i >> 11;
        int n = (ln & 15) + nt*16;
        int k = kc*32 + (ln >> 4)*8 + j;
        float val = W4[n*64 + k];
        uint ux = __float_as_uint(val);
        uint rh = (ux + 0x7FFFu + ((ux >> 16) & 1u)) & 0xFFFF0000u;
        float lof = val - __uint_as_float(rh);
        uint ul = __float_as_uint(lof);
        uint rl = (ul + 0x7FFFu + ((ul >> 16) & 1u)) >> 16;
        w4fh[i] = (ushort)(rh >> 16);
        w4fl[i] = (ushort)rl;
    }
}

// pair list: (pair index, scalar a, scalar b)
#define PAIRS(M) M(0,0,1) M(1,2,3) M(2,4,5) M(3,6,7) M(4,8,9) M(5,10,11) \
  M(6,12,13) M(7,14,15) M(8,16,17) M(9,18,19) M(10,20,21) M(11,22,23) \
  M(12,24,25) M(13,26,27) M(14,28,29) M(15,30,31)

#define MF3(D, AH, AL, BH, BL) \
    D = __builtin_amdgcn_mfma_f32_16x16x32_bf16(AL, BH, D, 0, 0, 0); \
    D = __builtin_amdgcn_mfma_f32_16x16x32_bf16(AH, BL, D, 0, 0, 0); \
    D = __builtin_amdgcn_mfma_f32_16x16x32_bf16(AH, BH, D, 0, 0, 0);

// ---------------- VFE (unchanged from round 11) ----------------
__global__ __launch_bounds__(256, 3) void vfe_kernel(
    const float* __restrict__ feat, const int* __restrict__ coors,
    const int* __restrict__ nvx,
    const float* __restrict__ W1, const float* __restrict__ W2,
    const float* __restrict__ W3,
    const ushort* __restrict__ w4fh, const ushort* __restrict__ w4fl,
    const float* __restrict__ fold,
    float* __restrict__ voxelwise, int* __restrict__ cnt,
    int* __restrict__ list, int* __restrict__ nact, int* __restrict__ act)
{
    __shared__ char ldsbuf[4*8704];
    int tid = threadIdx.x;
    int lane = tid & 63;
    int wv = tid >> 6;
    int quad = lane >> 4;
    int v = blockIdx.x * 8 + (tid >> 5);
    int vA = blockIdx.x * 8 + 2*wv;
    int t = tid & 31;
    uint*  x3w  = (uint*)(ldsbuf + wv*8704);
    float* xw   = (float*)x3w;
    float* aggL = (float*)(ldsbuf + wv*8704 + 8448);

    const float* fp = feat + (v*32 + t)*8;
    float4 fa = *(const float4*)fp;
    float4 fb = *(const float4*)(fp+4);
    int numv = nvx[v];
    float maskf = (t < numv) ? 1.f : 0.f;

#define D1(o) float x1_##o; float m1_##o;
    REP8_0(D1)
#undef D1
#define FE1(o) { const float* w = W1 + (o)*8; \
    float ya = fa.x*w[0] + fa.y*w[1]; float yb = fa.z*w[2] + fa.w*w[3]; \
    float yc = fb.x*w[4] + fb.y*w[5]; float yd = fb.z*w[6] + fb.w*w[7]; \
    float yy = ((ya+yb)+(yc+yd)) * fold[(o)] + fold[8+(o)]; \
    x1_##o = mishf(yy); }
    REP8_0(FE1)
#undef FE1
#define P1(o) { float a = x1_##o; WMAX32(a); m1_##o = a; }
    REP8_0(P1)
#undef P1

    f32x2 x1p_0 = {x1_0,x1_1}, x1p_1 = {x1_2,x1_3}, x1p_2 = {x1_4,x1_5}, x1p_3 = {x1_6,x1_7};
    f32x2 m1p_0 = {m1_0,m1_1}, m1p_1 = {m1_2,m1_3}, m1p_2 = {m1_4,m1_5}, m1p_3 = {m1_6,m1_7};

#define D2(o) float x2_##o; float agg_##o;
    REP32_0(D2)
#undef D2
#define FE2(o) { const f32x2* wp = (const f32x2*)(W2 + (o)*16); \
    f32x2 sa = x1p_0*wp[0]; sa += x1p_1*wp[1]; \
    f32x2 sb = x1p_2*wp[2]; sb += x1p_3*wp[3]; \
    f32x2 sc = m1p_0*wp[4]; sc += m1p_1*wp[5]; \
    f32x2 sd = m1p_2*wp[6]; sd += m1p_3*wp[7]; \
    sa += sb; sc += sd; sa += sc; \
    float yy = (sa.x + sa.y) * fold[16+(o)] + fold[48+(o)]; \
    x2_##o = mishf(yy); }
    REP32_0(FE2)
#undef FE2
#define P2(o) { float a = x2_##o; WMAX32(a); agg_##o = a; }
    REP32_0(P2)
#undef P2

#define PX(i,a,b) f32x2 x2p_##i = {x2_##a, x2_##b}; f32x2 aggp_##i = {agg_##a, agg_##b};
    PAIRS(PX)
#undef PX

    const f32x2* wap = (const f32x2*)(W3 + t*64 + 32);
    const f32x2* wbp = (const f32x2*)(W3 + (t+32)*64 + 32);
    f32x2 yp1 = {0.f,0.f}, yp2 = {0.f,0.f};
#define YG(i) yp1 += aggp_##i * wap[i]; yp2 += aggp_##i * wbp[i];
    REP16_0(YG)
#undef YG
    float yagg1 = yp1.x + yp1.y, yagg2 = yp2.x + yp2.y;

    f32x2 maskp = {maskf, maskf};
#define MSK(i) x2p_##i *= maskp; aggp_##i *= maskp;
    REP16_0(MSK)
#undef MSK

    if (t == 0) {
        float* ag = aggL + (lane >> 5)*32;
#define AGW(i) ag[2*(i)] = aggp_##i.x; ag[2*(i)+1] = aggp_##i.y;
        REP16_0(AGW)
#undef AGW
    }

    int nA = __shfl(numv, 0);
    int nB = __shfl(numv, 32);

#define DD(i) f32x4 d_##i = {0.f,0.f,0.f,0.f};
    REP16_0(DD)
#undef DD

    for (int kc = 0; kc < 2; kc++) {
        float ysrc = kc ? yagg2 : yagg1;
        for (int o = 0; o < 32; o++) {
            int og = kc*32 + o;
            const f32x2* wp = (const f32x2*)(W3 + og*64);
            f32x2 s0 = x2p_0*wp[0];  s0 += x2p_1*wp[1];  s0 += x2p_2*wp[2];  s0 += x2p_3*wp[3];
            f32x2 s1 = x2p_4*wp[4];  s1 += x2p_5*wp[5];  s1 += x2p_6*wp[6];  s1 += x2p_7*wp[7];
            f32x2 s2 = x2p_8*wp[8];  s2 += x2p_9*wp[9];  s2 += x2p_10*wp[10]; s2 += x2p_11*wp[11];
            f32x2 s3 = x2p_12*wp[12]; s3 += x2p_13*wp[13]; s3 += x2p_14*wp[14]; s3 += x2p_15*wp[15];
            s0 += s1; s2 += s3; s0 += s2;
            float ya = __shfl(ysrc, o, 32);
            float yy = (s0.x + s0.y) + maskf * ya;
            yy = yy * fold[80+og] + fold[144+og];
            x3w[lane*33 + o] = splitbf(mishf(yy));
        }
        __syncthreads();

        const uint4* bh = (const uint4*)w4fh + (kc*4)*64 + lane;
        const uint4* bl = (const uint4*)w4fl + (kc*4)*64 + lane;

#define MFNT(D, nt) { \
    uint4 h = bh[(nt)*64]; uint4 l = bl[(nt)*64]; \
    bf16x8 Bh = mkbf8(h.x,h.y,h.z,h.w); bf16x8 Bl = mkbf8(l.x,l.y,l.z,l.w); \
    MF3(D, Ah, Al, Bh, Bl) }

#define DOMT(mt, D0, D1, D2, D3) { \
    int aoff = ((lane & 15) + 16*(mt))*33 + quad*8; \
    uint u0 = x3w[aoff+0], u1 = x3w[aoff+1], u2 = x3w[aoff+2], u3 = x3w[aoff+3]; \
    uint u4 = x3w[aoff+4], u5 = x3w[aoff+5], u6 = x3w[aoff+6], u7 = x3w[aoff+7]; \
    bf16x8 Ah = mkbf8(__builtin_amdgcn_perm(u1,u0,0x05040100), __builtin_amdgcn_perm(u3,u2,0x05040100), \
                      __builtin_amdgcn_perm(u5,u4,0x05040100), __builtin_amdgcn_perm(u7,u6,0x05040100)); \
    bf16x8 Al = mkbf8(__builtin_amdgcn_perm(u1,u0,0x07060302), __builtin_amdgcn_perm(u3,u2,0x07060302), \
                      __builtin_amdgcn_perm(u5,u4,0x07060302), __builtin_amdgcn_perm(u7,u6,0x07060302)); \
    MFNT(d_##D0, 0) MFNT(d_##D1, 1) MFNT(d_##D2, 2) MFNT(d_##D3, 3) }

        DOMT(0, 0, 1, 2, 3)
        DOMT(1, 4, 5, 6, 7)
        DOMT(2, 8, 9, 10, 11)
        DOMT(3, 12, 13, 14, 15)
#undef DOMT
#undef MFNT
        __syncthreads();
    }

#define XWR(i) xw[lane*33 + 2*(i)] = x2p_##i.x; xw[lane*33 + 2*(i)+1] = x2p_##i.y;
    REP16_0(XWR)
#undef XWR
    __syncthreads();

    int c0 = lane & 15;
    float s0f = fold[208+c0],    t0f = fold[272+c0];
    float s1f = fold[208+16+c0], t1f = fold[272+16+c0];
    float s2f = fold[208+32+c0], t2f = fold[272+32+c0];
    float s3f = fold[208+48+c0], t3f = fold[272+48+c0];
    float rA2 = aggL[c0],      rA3 = aggL[16+c0];
    float rB2 = aggL[32+c0],   rB3 = aggL[48+c0];
    float pA0=-3.4e38f, pA1=-3.4e38f, pA2=-3.4e38f, pA3=-3.4e38f;
    float pB0=-3.4e38f, pB1=-3.4e38f, pB2=-3.4e38f, pB3=-3.4e38f;

#define FTP(D, mt, nt, SS, TT, PV) { \
    int nv = ((mt) >> 1) ? nB : nA; \
    int rf = quad*4 + 16*(mt); \
    int rt = quad*4 + 16*((mt)&1); \
    int cb = c0 + 16*(nt); \
    float m0=(rt+0<nv)?1.f:0.f, m1=(rt+1<nv)?1.f:0.f, m2=(rt+2<nv)?1.f:0.f, m3=(rt+3<nv)?1.f:0.f; \
    float y0 = mishf(D.x*SS + TT)*m0 + xw[(rf+0)*33 + cb]; \
    float y1 = mishf(D.y*SS + TT)*m1 + xw[(rf+1)*33 + cb]; \
    float y2 = mishf(D.z*SS + TT)*m2 + xw[(rf+2)*33 + cb]; \
    float y3 = mishf(D.w*SS + TT)*m3 + xw[(rf+3)*33 + cb]; \
    PV = fmaxf(PV, fmaxf(fmaxf(y0,y1), fmaxf(y2,y3))); }

#define FTA(D, mt, nt, SS, TT, AG, PV) { \
    int nv = ((mt) >> 1) ? nB : nA; \
    int rt = quad*4 + 16*((mt)&1); \
    float m0=(rt+0<nv)?1.f:0.f, m1=(rt+1<nv)?1.f:0.f, m2=(rt+2<nv)?1.f:0.f, m3=(rt+3<nv)?1.f:0.f; \
    float y0 = (mishf(D.x*SS + TT) + AG)*m0; \
    float y1 = (mishf(D.y*SS + TT) + AG)*m1; \
    float y2 = (mishf(D.z*SS + TT) + AG)*m2; \
    float y3 = (mishf(D.w*SS + TT) + AG)*m3; \
    PV = fmaxf(PV, fmaxf(fmaxf(y0,y1), fmaxf(y2,y3))); }

    FTP(d_0, 0, 0, s0f, t0f, pA0)  FTP(d_1, 0, 1, s1f, t1f, pA1)
    FTA(d_2, 0, 2, s2f, t2f, rA2, pA2)  FTA(d_3, 0, 3, s3f, t3f, rA3, pA3)
    FTP(d_4, 1, 0, s0f, t0f, pA0)  FTP(d_5, 1, 1, s1f, t1f, pA1)
    FTA(d_6, 1, 2, s2f, t2f, rA2, pA2)  FTA(d_7, 1, 3, s3f, t3f, rA3, pA3)
    FTP(d_8, 2, 0, s0f, t0f, pB0)  FTP(d_9, 2, 1, s1f, t1f, pB1)
    FTA(d_10, 2, 2, s2f, t2f, rB2, pB2)  FTA(d_11, 2, 3, s3f, t3f, rB3, pB3)
    FTP(d_12, 3, 0, s0f, t0f, pB0)  FTP(d_13, 3, 1, s1f, t1f, pB1)
    FTA(d_14, 3, 2, s2f, t2f, rB2, pB2)  FTA(d_15, 3, 3, s3f, t3f, rB3, pB3)
#undef FTP
#undef FTA

#define RED(p) p = fmaxf(p, __shfl_xor(p, 16)); p = fmaxf(p, __shfl_xor(p, 32));
    RED(pA0) RED(pA1) RED(pA2) RED(pA3) RED(pB0) RED(pB1) RED(pB2) RED(pB3)
#undef RED

    if (quad == 0) {
        float* vwA = voxelwise + vA*64;
        vwA[c0] = pA0; vwA[c0+16] = pA1; vwA[c0+32] = pA2; vwA[c0+48] = pA3;
        float* vwB = voxelwise + (vA+1)*64;
        vwB[c0] = pB0; vwB[c0+16] = pB1; vwB[c0+32] = pB2; vwB[c0+48] = pB3;
    }

    if (t == 0) {
        int cell = coors[v*2] * BEVW + coors[v*2+1];
        int pos = atomicAdd(&cnt[cell], 1);
        if (pos < 16) list[cell*16 + pos] = v;
        if (pos == 0) { int k = atomicAdd(nact, 1); act[k] = cell; }
    }
}

// ---------------- BFE front: 1 wave = 1 cell; also records idx[cell]=aidx ----------------
__global__ __launch_bounds__(256) void bfe_front(
    const int* __restrict__ nact, const int* __restrict__ act,
    const int* __restrict__ cnt, const int* __restrict__ list,
    const float* __restrict__ voxelwise,
    const float* __restrict__ W1g, const float* __restrict__ W2g,
    const float* __restrict__ fold, float* __restrict__ x17g,
    int* __restrict__ idx)
{
    int n_act = *nact;
    int aidx = blockIdx.x * 4 + (threadIdx.x >> 6);
    if (aidx >= n_act) return;

    int lane = threadIdx.x & 63;
    int g = lane >> 2, ii = lane & 3;
    int cell = act[aidx];
    int numv = min(cnt[cell], 16);
    if (lane == 0) idx[cell] = aidx;

    int myidx = (lane < numv) ? list[cell*16 + lane] : (0x40000000 + lane);
    int rank = 0;
    for (int j = 0; j < numv; j++) { int vj = __shfl(myidx, j); rank += (vj < myidx) ? 1 : 0; }
    if (lane >= numv) rank = lane;
    int sorted = __builtin_amdgcn_ds_permute(rank << 2, myidx);

#define YD(q) float y_##q = 0.f;
    REP16_0(YD)
#undef YD
    for (int p = 0; p < numv; p++) {
        int sv = __shfl(sorted, p);
        float val = voxelwise[sv*64 + lane];
        const float* w = W1g + g*256 + p;
#define BF1(q) y_##q += val * w[(q)*16];
        REP16_0(BF1)
#undef BF1
    }
#define BN1(q) { float yy = y_##q * fold[592 + g*16 + (q)] + fold[848 + g*16 + (q)]; \
    yy = mishf(yy); y_##q = ((q) < numv) ? yy : 0.f; }
    REP16_0(BN1)
#undef BN1

    float z0 = 0.f, z1 = 0.f;
#define BF2(p) z0 += y_##p * W2g[g*32 + (p)]; z1 += y_##p * W2g[g*32 + 16 + (p)];
    REP16_0(BF2)
#undef BF2
    z0 = mishf(z0 * fold[1104 + g*2 + 0] + fold[1136 + g*2 + 0]);
    z1 = mishf(z1 * fold[1104 + g*2 + 1] + fold[1136 + g*2 + 1]);

    int k0 = ii*32 + g*2;
    *(float2*)(x17g + aidx*128 + k0) = make_float2(z0, z1);
}

// ---------------- bfe3 fused: x19 written compactly back into x17g ----------------
// (Round-11 wrote 4.67M lone 4B stores into the 110MB out -> ~600MB write-allocate
// traffic. Now each block's 32KB x17g window stays L2-resident -> full-line merges.)
__global__ __launch_bounds__(512, 4) void bfe3_fused(
    const int* __restrict__ nactp,
    const float* __restrict__ W3, const float* __restrict__ fold,
    float* __restrict__ x17g)
{
    __shared__ float XL[64*128];   // float4-chunk XOR swizzle: chunk kc at kc^(c&31)
    int tid = threadIdx.x;
    int n_act = *nactp;
    int cb = blockIdx.x * 64;

    for (int i = tid; i < 64*32; i += 512) {
        int c = i >> 5, kc = i & 31;
        float4 val = (cb + c < n_act) ? ((const float4*)x17g)[(size_t)(cb+c)*32 + kc]
                                      : make_float4(0.f,0.f,0.f,0.f);
        ((float4*)XL)[c*32 + (kc ^ (c & 31))] = val;
    }
    __syncthreads();

    int wv = __builtin_amdgcn_readfirstlane(tid >> 6);
    int c  = tid & 63;
    int ob = wv * 16;
    int cswz = c & 31;
    const float4* xrow = (const float4*)XL + c*32;
    const float4* W4p = (const float4*)W3;

#define DECLB(q) f32x2 ap_##q = {0.f, 0.f};
#define ACCB(q) { const f32x2* wp_ = (const f32x2*)(W4p + (ob+(q))*32 + kc); \
    ap_##q += xv01 * wp_[0]; ap_##q += xv23 * wp_[1]; }
#define ACTB(q) float a_##q; { float yy = (ap_##q.x + ap_##q.y) * fold[336+ob+(q)] + fold[464+ob+(q)]; a_##q = mishf(yy); }
    {
        REP16_0(DECLB)
        for (int kc = 0; kc < 32; kc++) {
            float4 xv = xrow[kc ^ cswz];
            f32x2 xv01 = {xv.x, xv.y}, xv23 = {xv.z, xv.w};
            REP16_0(ACCB)
        }
        REP16_0(ACTB)
        __syncthreads();   // everyone done READING XL
        ((float4*)XL)[c*32 + ((wv*4 + 0) ^ cswz)] = make_float4(a_0,  a_1,  a_2,  a_3);
        ((float4*)XL)[c*32 + ((wv*4 + 1) ^ cswz)] = make_float4(a_4,  a_5,  a_6,  a_7);
        ((float4*)XL)[c*32 + ((wv*4 + 2) ^ cswz)] = make_float4(a_8,  a_9,  a_10, a_11);
        ((float4*)XL)[c*32 + ((wv*4 + 3) ^ cswz)] = make_float4(a_12, a_13, a_14, a_15);
    }
    __syncthreads();

    {
        const float4* yrow = (const float4*)XL + c*32;
        REP16_0(DECLB)
        for (int kc = 0; kc < 32; kc++) {
            float4 xv = yrow[kc ^ cswz];
            f32x2 xv01 = {xv.x, xv.y}, xv23 = {xv.z, xv.w};
            REP16_0(ACCB)
        }
        REP16_0(ACTB)
        // x19 back into x17g[cell][ch] (block window = 32KB, L2-merged)
        float4* dst = (float4*)(x17g + (size_t)(cb + c)*128 + ob);
        dst[0] = make_float4(a_0,  a_1,  a_2,  a_3);
        dst[1] = make_float4(a_4,  a_5,  a_6,  a_7);
        dst[2] = make_float4(a_8,  a_9,  a_10, a_11);
        dst[3] = make_float4(a_12, a_13, a_14, a_15);
    }
#undef DECLB
#undef ACCB
#undef ACTB
}

// ---------------- bev_write: tiled transpose-scatter, replaces the 110MB memset ----
// block = (cx, 64-cell cy chunk); gathers x19 rows (full-line reads, 0 for empty),
// LDS transpose [c][cell] pad-65, writes out[c][cx][cy] as 64-lane 256B runs.
__global__ __launch_bounds__(512, 2) void bev_write(
    const int* __restrict__ idx, const float* __restrict__ x19c,
    float* __restrict__ out)
{
    __shared__ float XT[128*65];
    int bid = blockIdx.x;
    int cx = bid % BEVW;
    int cy0 = (bid / BEVW) << 6;
    int tid = threadIdx.x;

    int cell_l = tid >> 3;          // 0..63
    int chq = (tid & 7) << 4;       // 0,16,..,112
    int cy = cy0 + cell_l;
    float4 v0 = make_float4(0.f,0.f,0.f,0.f), v1 = v0, v2 = v0, v3 = v0;
    if (cy < BEVH) {
        int ai = idx[cy*BEVW + cx];
        if (ai >= 0) {
            const float4* src = (const float4*)(x19c + (size_t)ai*128 + chq);
            v0 = src[0]; v1 = src[1]; v2 = src[2]; v3 = src[3];
        }
    }
    float* d = XT + chq*65 + cell_l;
    d[0*65]=v0.x;  d[1*65]=v0.y;  d[2*65]=v0.z;  d[3*65]=v0.w;
    d[4*65]=v1.x;  d[5*65]=v1.y;  d[6*65]=v1.z;  d[7*65]=v1.w;
    d[8*65]=v2.x;  d[9*65]=v2.y;  d[10*65]=v2.z; d[11*65]=v2.w;
    d[12*65]=v3.x; d[13*65]=v3.y; d[14*65]=v3.z; d[15*65]=v3.w;
    __syncthreads();

    int wv2 = tid >> 6, lane = tid & 63;
    int cyw = cy0 + lane;
    if (cyw < BEVH) {
        float* op = out + cx*BEVH + cyw;
#pragma unroll
        for (int k = 0; k < 16; k++) {
            int c = (wv2 << 4) + k;
            op[(size_t)c*NCELL] = XT[c*65 + lane];
        }
    }
}

extern "C" void kernel_launch(void* const* d_in, const int* in_sizes, int n_in,
                              void* d_out, int out_size, void* d_ws, size_t ws_size,
                              hipStream_t stream) {
    const float* features = (const float*)d_in[0];
    const int*   coors    = (const int*)d_in[1];
    const int*   num_vox  = (const int*)d_in[2];
    const float* vfe1_W   = (const float*)d_in[3];
    const float* vfe1_bn  = (const float*)d_in[4];
    const float* vfe2_W   = (const float*)d_in[5];
    const float* vfe2_bn  = (const float*)d_in[6];
    const float* vfe3_W   = (const float*)d_in[7];
    const float* vfe3_bn  = (const float*)d_in[8];
    const float* vfe4_W   = (const float*)d_in[9];
    const float* vfe4_bn  = (const float*)d_in[10];
    const float* bfe1_W   = (const float*)d_in[11];
    const float* bfe1_bn  = (const float*)d_in[12];
    const float* bfe2_W   = (const float*)d_in[13];
    const float* bfe2_bn  = (const float*)d_in[14];
    const float* bfe3_W   = (const float*)d_in[15];
    const float* bfe3_bn  = (const float*)d_in[16];
    float* out = (float*)d_out;

    char* ws = (char*)d_ws;
    int*    nact      = (int*)ws;
    int*    cnt       = (int*)(ws + 256);
    int*    list      = (int*)(ws + 857600);
    float*  voxelwise = (float*)(ws + 14571008);
    int*    act       = (int*)(ws + 24811008);
    float*  x17g      = (float*)(ws + 24971008);
    float*  fold      = (float*)(ws + 45451008);
    ushort* w4fh      = (ushort*)(ws + 45455680);
    ushort* w4fl      = (ushort*)(ws + 45463872);
    int*    idx       = (int*)(ws + 45472064);

    (void)hipMemsetAsync(ws, 0, 857600, stream);          // nact + cnt
    (void)hipMemsetAsync(idx, 0xFF, (size_t)NCELL*4, stream);  // idx = -1

    setup_kernel<<<1, 256, 0, stream>>>(vfe1_bn, vfe2_bn, vfe3_bn, vfe4_bn,
                                        bfe1_bn, bfe2_bn, bfe3_bn, vfe4_W,
                                        fold, w4fh, w4fl);
    vfe_kernel<<<NVOX/8, 256, 0, stream>>>(features, coors, num_vox,
                                           vfe1_W, vfe2_W, vfe3_W, w4fh, w4fl, fold,
                                           voxelwise, cnt, list, nact, act);
    bfe_front<<<NVOX/4, 256, 0, stream>>>(nact, act, cnt, list, voxelwise,
                                          bfe1_W, bfe2_W, fold, x17g, idx);
    bfe3_fused<<<(NVOX+63)/64, 512, 0, stream>>>(nact, bfe3_W, fold, x17g);
    bev_write<<<BEVW*8, 512, 0, stream>>>(idx, x17g, out);
}

// Round 13
// 525.611 us; speedup vs baseline: 1.2356x; 1.0664x over previous
//
#include <hip/hip_runtime.h>

#define BEVW 432
#define BEVH 496
#define NCELL (BEVW*BEVH)      // 214272
#define NVOX  40000
#define EPSB  1e-5f

typedef float f32x2 __attribute__((ext_vector_type(2)));
typedef float f32x4 __attribute__((ext_vector_type(4)));
typedef unsigned int u32x4 __attribute__((ext_vector_type(4)));
typedef short bf16x8 __attribute__((ext_vector_type(8)));

// ---- repeat macros ----
#define REP8_0(M)  M(0) M(1) M(2) M(3) M(4) M(5) M(6) M(7)
#define REP8_8(M)  M(8) M(9) M(10) M(11) M(12) M(13) M(14) M(15)
#define REP8_16(M) M(16) M(17) M(18) M(19) M(20) M(21) M(22) M(23)
#define REP8_24(M) M(24) M(25) M(26) M(27) M(28) M(29) M(30) M(31)
#define REP16_0(M)  REP8_0(M)  REP8_8(M)
#define REP32_0(M) REP16_0(M) REP8_16(M) REP8_24(M)

// ---------------- workspace layout (bytes) ----------------
// 0        : int nact (zeroed) | 256: int cnt[NCELL] (zeroed)
// 857600   : int list[NCELL*16]
// 14571008 : float voxelwise[NVOX*64]
// 24811008 : int act[NVOX]
// 24971008 : float x17g[NVOX*128]   (x17, then x19 in-place)
// 45451008 : float fold[1168]
// 45455680 : ushort w4fh[4096] | 45463872 : ushort w4fl[4096]
// 45472064 : int idx[NCELL] (memset 0xFF)
// 46329344 : ushort w3fh[4096] | 46337536 : ushort w3fl[4096]

__device__ __forceinline__ float mishf(float y) {
    float e = __expf(fminf(y, 40.f));
    float n = e * (e + 2.f);
    return y * n * __builtin_amdgcn_rcpf(n + 2.f);
}

template <int CTRL>
__device__ __forceinline__ float dppmaxf(float a) {
    int p = __builtin_amdgcn_update_dpp(0, __float_as_int(a), CTRL, 0xF, 0xF, true);
    return fmaxf(a, __int_as_float(p));
}
#define WMAX32(a) { \
    a = dppmaxf<0xB1>(a); \
    a = dppmaxf<0x4E>(a); \
    a = dppmaxf<0x141>(a); \
    a = dppmaxf<0x140>(a); \
    a = fmaxf(a, __int_as_float(__builtin_amdgcn_ds_swizzle(__float_as_int(a), 0x401F))); }

__device__ __forceinline__ bf16x8 mkbf8(uint a, uint b, uint c, uint d) {
    u32x4 t = {a, b, c, d};
    return __builtin_bit_cast(bf16x8, t);
}

// split fp32 -> (hi bf16 | lo bf16 << 16), RNE both
__device__ __forceinline__ uint splitbf(float x) {
    uint ux = __float_as_uint(x);
    uint rh = (ux + 0x7FFFu + ((ux >> 16) & 1u)) & 0xFFFF0000u;
    float lof = x - __uint_as_float(rh);
    uint ul = __float_as_uint(lof);
    uint rl = (ul + 0x7FFFu + ((ul >> 16) & 1u)) >> 16;
    return (rh >> 16) | (rl << 16);
}

// fold layout: vfe1 s@0 t@8 | vfe2 s@16 t@48 | vfe3 s@80 t@144 | vfe4 s@208 t@272
// bfe3 s@336 t@464 | bfe1 s@592 t@848 | bfe2 s@1104 t@1136
__global__ __launch_bounds__(256) void setup_kernel(
    const float* __restrict__ vbn1, const float* __restrict__ vbn2,
    const float* __restrict__ vbn3, const float* __restrict__ vbn4,
    const float* __restrict__ bbn1, const float* __restrict__ bbn2,
    const float* __restrict__ bbn3, const float* __restrict__ W4,
    const float* __restrict__ W3g,
    float* __restrict__ fold, ushort* __restrict__ w4fh, ushort* __restrict__ w4fl,
    ushort* __restrict__ w3fh, ushort* __restrict__ w3fl)
{
    int tid = threadIdx.x;
    if (tid < 8)  { float s = vbn1[tid]/sqrtf(vbn1[24+tid]+EPSB);  fold[tid]      = s; fold[8+tid]   = vbn1[8+tid]  - vbn1[16+tid]*s; }
    if (tid < 32) { float s = vbn2[tid]/sqrtf(vbn2[96+tid]+EPSB);  fold[16+tid]   = s; fold[48+tid]  = vbn2[32+tid] - vbn2[64+tid]*s; }
    if (tid < 64) { float s = vbn3[tid]/sqrtf(vbn3[192+tid]+EPSB); fold[80+tid]   = s; fold[144+tid] = vbn3[64+tid] - vbn3[128+tid]*s; }
    if (tid < 64) { float s = vbn4[tid]/sqrtf(vbn4[192+tid]+EPSB); fold[208+tid]  = s; fold[272+tid] = vbn4[64+tid] - vbn4[128+tid]*s; }
    if (tid < 128){ float s = bbn3[tid]/sqrtf(bbn3[384+tid]+EPSB); fold[336+tid]  = s; fold[464+tid] = bbn3[128+tid]- bbn3[256+tid]*s; }
    { int g = tid >> 4, q = tid & 15;
      const float* b = bbn1 + g*64;
      float s = b[q]/sqrtf(b[48+q]+EPSB);
      fold[592+tid] = s; fold[848+tid] = b[16+q] - b[32+q]*s; }
    if (tid < 32) { int g = tid >> 1, c = tid & 1;
      const float* b = bbn2 + g*8;
      float s = b[c]/sqrtf(b[6+c]+EPSB);
      fold[1104+tid] = s; fold[1136+tid] = b[2+c] - b[4+c]*s; }

    // B-fragments (B[k][n] = W[n][k]) split bf16 hi/lo, for W4^T (fe4) and W3^T (fe3).
    // frag idx = ((kc*4 + nt)*64 + lane)*8 + j ; n = (lane&15)+16nt ; k = kc*32 + (lane>>4)*8 + j
    for (int i = tid; i < 4096; i += 256) {
        int j = i & 7, ln = (i >> 3) & 63, nt = (i >> 9) & 3, kc = i >> 11;
        int n = (ln & 15) + nt*16;
        int k = kc*32 + (ln >> 4)*8 + j;
        {
            float val = W4[n*64 + k];
            uint ux = __float_as_uint(val);
            uint rh = (ux + 0x7FFFu + ((ux >> 16) & 1u)) & 0xFFFF0000u;
            float lof = val - __uint_as_float(rh);
            uint ul = __float_as_uint(lof);
            uint rl = (ul + 0x7FFFu + ((ul >> 16) & 1u)) >> 16;
            w4fh[i] = (ushort)(rh >> 16);
            w4fl[i] = (ushort)rl;
        }
        {
            float val = W3g[n*64 + k];
            uint ux = __float_as_uint(val);
            uint rh = (ux + 0x7FFFu + ((ux >> 16) & 1u)) & 0xFFFF0000u;
            float lof = val - __uint_as_float(rh);
            uint ul = __float_as_uint(lof);
            uint rl = (ul + 0x7FFFu + ((ul >> 16) & 1u)) >> 16;
            w3fh[i] = (ushort)(rh >> 16);
            w3fl[i] = (ushort)rl;
        }
    }
}

// pair list
#define PAIRS(M) M(0,0,1) M(1,2,3) M(2,4,5) M(3,6,7) M(4,8,9) M(5,10,11) \
  M(6,12,13) M(7,14,15) M(8,16,17) M(9,18,19) M(10,20,21) M(11,22,23) \
  M(12,24,25) M(13,26,27) M(14,28,29) M(15,30,31)

#define MF3(D, AH, AL, BH, BL) \
    D = __builtin_amdgcn_mfma_f32_16x16x32_bf16(AL, BH, D, 0, 0, 0); \
    D = __builtin_amdgcn_mfma_f32_16x16x32_bf16(AH, BL, D, 0, 0, 0); \
    D = __builtin_amdgcn_mfma_f32_16x16x32_bf16(AH, BH, D, 0, 0, 0);

// A-tile group: A frags from LDS rows (stride 33), 4 B frags from L1, 12 MFMAs.
#define DOMTX(SRCP, BHP, BLP, mt, D0, D1, D2, D3) { \
    const uint* ap_ = (SRCP) + ((lane & 15) + 16*(mt))*33 + quad*8; \
    uint u0 = ap_[0], u1 = ap_[1], u2 = ap_[2], u3 = ap_[3]; \
    uint u4 = ap_[4], u5 = ap_[5], u6 = ap_[6], u7 = ap_[7]; \
    bf16x8 Ah = mkbf8(__builtin_amdgcn_perm(u1,u0,0x05040100), __builtin_amdgcn_perm(u3,u2,0x05040100), \
                      __builtin_amdgcn_perm(u5,u4,0x05040100), __builtin_amdgcn_perm(u7,u6,0x05040100)); \
    bf16x8 Al = mkbf8(__builtin_amdgcn_perm(u1,u0,0x07060302), __builtin_amdgcn_perm(u3,u2,0x07060302), \
                      __builtin_amdgcn_perm(u5,u4,0x07060302), __builtin_amdgcn_perm(u7,u6,0x07060302)); \
    { uint4 h = (BHP)[0];   uint4 l = (BLP)[0];   bf16x8 Bh = mkbf8(h.x,h.y,h.z,h.w), Bl = mkbf8(l.x,l.y,l.z,l.w); MF3(D0, Ah, Al, Bh, Bl) } \
    { uint4 h = (BHP)[64];  uint4 l = (BLP)[64];  bf16x8 Bh = mkbf8(h.x,h.y,h.z,h.w), Bl = mkbf8(l.x,l.y,l.z,l.w); MF3(D1, Ah, Al, Bh, Bl) } \
    { uint4 h = (BHP)[128]; uint4 l = (BLP)[128]; bf16x8 Bh = mkbf8(h.x,h.y,h.z,h.w), Bl = mkbf8(l.x,l.y,l.z,l.w); MF3(D2, Ah, Al, Bh, Bl) } \
    { uint4 h = (BHP)[192]; uint4 l = (BLP)[192]; bf16x8 Bh = mkbf8(h.x,h.y,h.z,h.w), Bl = mkbf8(l.x,l.y,l.z,l.w); MF3(D3, Ah, Al, Bh, Bl) } }

// ---------------- VFE: fe3 AND fe4 on matrix cores (split-bf16) ----------------
// wave = 2 voxels. Masked x2 (split u32) staged to wave-private LDS (full K=64 incl
// agg half -> yagg machinery deleted; zero rows for invalid points are exact).
// fe3 = 96 MFMA -> bn/mish in C-layout -> x3 frags into freed agg region -> fe4 = 96 MFMA.
// Residual x2 read back hi+lo (err ~1e-5). No __syncthreads (all LDS wave-private,
// DS ops in-order per wave). LDS 17152 B/wave -> 2 blocks/CU.
__global__ __launch_bounds__(256, 2) void vfe_kernel(
    const float* __restrict__ feat, const int* __restrict__ coors,
    const int* __restrict__ nvx,
    const float* __restrict__ W1, const float* __restrict__ W2,
    const ushort* __restrict__ w3fh, const ushort* __restrict__ w3fl,
    const ushort* __restrict__ w4fh, const ushort* __restrict__ w4fl,
    const float* __restrict__ fold,
    float* __restrict__ voxelwise, int* __restrict__ cnt,
    int* __restrict__ list, int* __restrict__ nact, int* __restrict__ act)
{
    __shared__ char ldsbuf[4*17152];   // per wave: x2s[2][64][33] u32 + aggL[64] f32
    int tid = threadIdx.x;
    int lane = tid & 63;
    int wv = tid >> 6;
    int quad = lane >> 4;
    int v = blockIdx.x * 8 + (tid >> 5);
    int vA = blockIdx.x * 8 + 2*wv;
    int t = tid & 31;
    uint*  x2s  = (uint*)(ldsbuf + wv*17152);
    float* aggL = (float*)(ldsbuf + wv*17152 + 16896);

    const float* fp = feat + (v*32 + t)*8;
    float4 fa = *(const float4*)fp;
    float4 fb = *(const float4*)(fp+4);
    int numv = nvx[v];
    float maskf = (t < numv) ? 1.f : 0.f;

    // ---- fe1 (8->8) + pool ----
#define D1(o) float x1_##o; float m1_##o;
    REP8_0(D1)
#undef D1
#define FE1(o) { const float* w = W1 + (o)*8; \
    float ya = fa.x*w[0] + fa.y*w[1]; float yb = fa.z*w[2] + fa.w*w[3]; \
    float yc = fb.x*w[4] + fb.y*w[5]; float yd = fb.z*w[6] + fb.w*w[7]; \
    float yy = ((ya+yb)+(yc+yd)) * fold[(o)] + fold[8+(o)]; \
    x1_##o = mishf(yy); }
    REP8_0(FE1)
#undef FE1
#define P1(o) { float a = x1_##o; WMAX32(a); m1_##o = a; }
    REP8_0(P1)
#undef P1

    f32x2 x1p_0 = {x1_0,x1_1}, x1p_1 = {x1_2,x1_3}, x1p_2 = {x1_4,x1_5}, x1p_3 = {x1_6,x1_7};
    f32x2 m1p_0 = {m1_0,m1_1}, m1p_1 = {m1_2,m1_3}, m1p_2 = {m1_4,m1_5}, m1p_3 = {m1_6,m1_7};

    // ---- fe2 (16->32) + pool ----
#define D2(o) float x2_##o; float agg_##o;
    REP32_0(D2)
#undef D2
#define FE2(o) { const f32x2* wp = (const f32x2*)(W2 + (o)*16); \
    f32x2 sa = x1p_0*wp[0]; sa += x1p_1*wp[1]; \
    f32x2 sb = x1p_2*wp[2]; sb += x1p_3*wp[3]; \
    f32x2 sc = m1p_0*wp[4]; sc += m1p_1*wp[5]; \
    f32x2 sd = m1p_2*wp[6]; sd += m1p_3*wp[7]; \
    sa += sb; sc += sd; sa += sc; \
    float yy = (sa.x + sa.y) * fold[16+(o)] + fold[48+(o)]; \
    x2_##o = mishf(yy); }
    REP32_0(FE2)
#undef FE2
#define P2(o) { float a = x2_##o; WMAX32(a); agg_##o = a; }
    REP32_0(P2)
#undef P2

#define PX(i,a,b) f32x2 x2p_##i = {x2_##a, x2_##b}; f32x2 aggp_##i = {agg_##a, agg_##b};
    PAIRS(PX)
#undef PX

    f32x2 maskp = {maskf, maskf};
#define MSK(i) x2p_##i *= maskp; aggp_##i *= maskp;
    REP16_0(MSK)
#undef MSK

    // aggL: exact fp32 agg (lane t==0 always valid -> masked == unmasked)
    if (t == 0) {
        float* ag = aggL + (lane >> 5)*32;
#define AGW(i) ag[2*(i)] = aggp_##i.x; ag[2*(i)+1] = aggp_##i.y;
        REP16_0(AGW)
#undef AGW
    }

    int nA = __shfl(numv, 0);
    int nB = __shfl(numv, 32);

    // ---- stage masked x2 split into LDS: chunk0 = ch 0..31, chunk1 = ch 32..63 ----
#define X2W(i) { \
    x2s[lane*33 + 2*(i)]          = splitbf(x2p_##i.x); \
    x2s[lane*33 + 2*(i)+1]        = splitbf(x2p_##i.y); \
    x2s[2112 + lane*33 + 2*(i)]   = splitbf(aggp_##i.x); \
    x2s[2112 + lane*33 + 2*(i)+1] = splitbf(aggp_##i.y); }
    REP16_0(X2W)
#undef X2W

    // ---- fe3: 96 MFMAs over K=64 ----
#define E_DECL(i) f32x4 e_##i = {0.f,0.f,0.f,0.f};
    REP16_0(E_DECL)
#undef E_DECL
    {
        const uint4* bh3 = (const uint4*)w3fh + lane;
        const uint4* bl3 = (const uint4*)w3fl + lane;
        DOMTX(x2s, bh3, bl3, 0, e_0, e_1, e_2, e_3)
        DOMTX(x2s, bh3, bl3, 1, e_4, e_5, e_6, e_7)
        DOMTX(x2s, bh3, bl3, 2, e_8, e_9, e_10, e_11)
        DOMTX(x2s, bh3, bl3, 3, e_12, e_13, e_14, e_15)
    }
    {
        const uint4* bh3 = (const uint4*)w3fh + 256 + lane;
        const uint4* bl3 = (const uint4*)w3fl + 256 + lane;
        const uint* sp = x2s + 2112;
        DOMTX(sp, bh3, bl3, 0, e_0, e_1, e_2, e_3)
        DOMTX(sp, bh3, bl3, 1, e_4, e_5, e_6, e_7)
        DOMTX(sp, bh3, bl3, 2, e_8, e_9, e_10, e_11)
        DOMTX(sp, bh3, bl3, 3, e_12, e_13, e_14, e_15)
    }

    // ---- fe3 epilogue (bn+mish+split, C-layout) interleaved with fe4 MFMA ----
    int c0 = lane & 15;
    uint* x3st = x2s + 2112;   // agg chunk reused as x3 staging (per 32-output chunk)
#define DD(i) f32x4 d_##i = {0.f,0.f,0.f,0.f};
    REP16_0(DD)
#undef DD

#define POST(TI, mt, nt) { \
    float s_ = fold[80 + c0 + 16*(nt)], tb_ = fold[144 + c0 + 16*(nt)]; \
    int col_ = c0 + 16*((nt)&1); \
    int rowb_ = quad*4 + 16*(mt); \
    x3st[(rowb_+0)*33 + col_] = splitbf(mishf(e_##TI.x * s_ + tb_)); \
    x3st[(rowb_+1)*33 + col_] = splitbf(mishf(e_##TI.y * s_ + tb_)); \
    x3st[(rowb_+2)*33 + col_] = splitbf(mishf(e_##TI.z * s_ + tb_)); \
    x3st[(rowb_+3)*33 + col_] = splitbf(mishf(e_##TI.w * s_ + tb_)); }

    { // output chunk 0: fe3 outputs 0..31 (nt 0,1)
        POST(0,0,0)  POST(1,0,1)
        POST(4,1,0)  POST(5,1,1)
        POST(8,2,0)  POST(9,2,1)
        POST(12,3,0) POST(13,3,1)
        const uint4* bh4 = (const uint4*)w4fh + lane;
        const uint4* bl4 = (const uint4*)w4fl + lane;
        DOMTX(x3st, bh4, bl4, 0, d_0, d_1, d_2, d_3)
        DOMTX(x3st, bh4, bl4, 1, d_4, d_5, d_6, d_7)
        DOMTX(x3st, bh4, bl4, 2, d_8, d_9, d_10, d_11)
        DOMTX(x3st, bh4, bl4, 3, d_12, d_13, d_14, d_15)
    }
    { // output chunk 1: fe3 outputs 32..63 (nt 2,3)
        POST(2,0,2)  POST(3,0,3)
        POST(6,1,2)  POST(7,1,3)
        POST(10,2,2) POST(11,2,3)
        POST(14,3,2) POST(15,3,3)
        const uint4* bh4 = (const uint4*)w4fh + 256 + lane;
        const uint4* bl4 = (const uint4*)w4fl + 256 + lane;
        DOMTX(x3st, bh4, bl4, 0, d_0, d_1, d_2, d_3)
        DOMTX(x3st, bh4, bl4, 1, d_4, d_5, d_6, d_7)
        DOMTX(x3st, bh4, bl4, 2, d_8, d_9, d_10, d_11)
        DOMTX(x3st, bh4, bl4, 3, d_12, d_13, d_14, d_15)
    }
#undef POST

    // ---- bn4 + mish + residual + pool in C layout ----
    float s0f = fold[208+c0],    t0f = fold[272+c0];
    float s1f = fold[208+16+c0], t1f = fold[272+16+c0];
    float s2f = fold[208+32+c0], t2f = fold[272+32+c0];
    float s3f = fold[208+48+c0], t3f = fold[272+48+c0];
    float rA2 = aggL[c0],      rA3 = aggL[16+c0];
    float rB2 = aggL[32+c0],   rB3 = aggL[48+c0];
    float pA0=-3.4e38f, pA1=-3.4e38f, pA2=-3.4e38f, pA3=-3.4e38f;
    float pB0=-3.4e38f, pB1=-3.4e38f, pB2=-3.4e38f, pB3=-3.4e38f;

#define RECON(u) (__uint_as_float((u)<<16) + __uint_as_float((u) & 0xFFFF0000u))
#define FTP(D, mt, nt, SS, TT, PV) { \
    int nv = ((mt) >> 1) ? nB : nA; \
    int rf = quad*4 + 16*(mt); \
    int rt = quad*4 + 16*((mt)&1); \
    int cb = c0 + 16*(nt); \
    float m0=(rt+0<nv)?1.f:0.f, m1=(rt+1<nv)?1.f:0.f, m2=(rt+2<nv)?1.f:0.f, m3=(rt+3<nv)?1.f:0.f; \
    uint ua_ = x2s[(rf+0)*33 + cb], ub_ = x2s[(rf+1)*33 + cb]; \
    uint uc_ = x2s[(rf+2)*33 + cb], ud_ = x2s[(rf+3)*33 + cb]; \
    float y0 = mishf(D.x*SS + TT)*m0 + RECON(ua_); \
    float y1 = mishf(D.y*SS + TT)*m1 + RECON(ub_); \
    float y2 = mishf(D.z*SS + TT)*m2 + RECON(uc_); \
    float y3 = mishf(D.w*SS + TT)*m3 + RECON(ud_); \
    PV = fmaxf(PV, fmaxf(fmaxf(y0,y1), fmaxf(y2,y3))); }

#define FTA(D, mt, nt, SS, TT, AG, PV) { \
    int nv = ((mt) >> 1) ? nB : nA; \
    int rt = quad*4 + 16*((mt)&1); \
    float m0=(rt+0<nv)?1.f:0.f, m1=(rt+1<nv)?1.f:0.f, m2=(rt+2<nv)?1.f:0.f, m3=(rt+3<nv)?1.f:0.f; \
    float y0 = (mishf(D.x*SS + TT) + AG)*m0; \
    float y1 = (mishf(D.y*SS + TT) + AG)*m1; \
    float y2 = (mishf(D.z*SS + TT) + AG)*m2; \
    float y3 = (mishf(D.w*SS + TT) + AG)*m3; \
    PV = fmaxf(PV, fmaxf(fmaxf(y0,y1), fmaxf(y2,y3))); }

    FTP(d_0, 0, 0, s0f, t0f, pA0)  FTP(d_1, 0, 1, s1f, t1f, pA1)
    FTA(d_2, 0, 2, s2f, t2f, rA2, pA2)  FTA(d_3, 0, 3, s3f, t3f, rA3, pA3)
    FTP(d_4, 1, 0, s0f, t0f, pA0)  FTP(d_5, 1, 1, s1f, t1f, pA1)
    FTA(d_6, 1, 2, s2f, t2f, rA2, pA2)  FTA(d_7, 1, 3, s3f, t3f, rA3, pA3)
    FTP(d_8, 2, 0, s0f, t0f, pB0)  FTP(d_9, 2, 1, s1f, t1f, pB1)
    FTA(d_10, 2, 2, s2f, t2f, rB2, pB2)  FTA(d_11, 2, 3, s3f, t3f, rB3, pB3)
    FTP(d_12, 3, 0, s0f, t0f, pB0)  FTP(d_13, 3, 1, s1f, t1f, pB1)
    FTA(d_14, 3, 2, s2f, t2f, rB2, pB2)  FTA(d_15, 3, 3, s3f, t3f, rB3, pB3)
#undef FTP
#undef FTA
#undef RECON

#define RED(p) p = fmaxf(p, __shfl_xor(p, 16)); p = fmaxf(p, __shfl_xor(p, 32));
    RED(pA0) RED(pA1) RED(pA2) RED(pA3) RED(pB0) RED(pB1) RED(pB2) RED(pB3)
#undef RED

    if (quad == 0) {
        float* vwA = voxelwise + vA*64;
        vwA[c0] = pA0; vwA[c0+16] = pA1; vwA[c0+32] = pA2; vwA[c0+48] = pA3;
        float* vwB = voxelwise + (vA+1)*64;
        vwB[c0] = pB0; vwB[c0+16] = pB1; vwB[c0+32] = pB2; vwB[c0+48] = pB3;
    }

    if (t == 0) {
        int cell = coors[v*2] * BEVW + coors[v*2+1];
        int pos = atomicAdd(&cnt[cell], 1);
        if (pos < 16) list[cell*16 + pos] = v;
        if (pos == 0) { int k = atomicAdd(nact, 1); act[k] = cell; }
    }
}

// ---------------- BFE front: 1 wave = 1 cell; records idx[cell]=aidx ----------------
__global__ __launch_bounds__(256) void bfe_front(
    const int* __restrict__ nact, const int* __restrict__ act,
    const int* __restrict__ cnt, const int* __restrict__ list,
    const float* __restrict__ voxelwise,
    const float* __restrict__ W1g, const float* __restrict__ W2g,
    const float* __restrict__ fold, float* __restrict__ x17g,
    int* __restrict__ idx)
{
    int n_act = *nact;
    int aidx = blockIdx.x * 4 + (threadIdx.x >> 6);
    if (aidx >= n_act) return;

    int lane = threadIdx.x & 63;
    int g = lane >> 2, ii = lane & 3;
    int cell = act[aidx];
    int numv = min(cnt[cell], 16);
    if (lane == 0) idx[cell] = aidx;

    int myidx = (lane < numv) ? list[cell*16 + lane] : (0x40000000 + lane);
    int rank = 0;
    for (int j = 0; j < numv; j++) { int vj = __shfl(myidx, j); rank += (vj < myidx) ? 1 : 0; }
    if (lane >= numv) rank = lane;
    int sorted = __builtin_amdgcn_ds_permute(rank << 2, myidx);

#define YD(q) float y_##q = 0.f;
    REP16_0(YD)
#undef YD
    for (int p = 0; p < numv; p++) {
        int sv = __shfl(sorted, p);
        float val = voxelwise[sv*64 + lane];
        const float* w = W1g + g*256 + p;
#define BF1(q) y_##q += val * w[(q)*16];
        REP16_0(BF1)
#undef BF1
    }
#define BN1(q) { float yy = y_##q * fold[592 + g*16 + (q)] + fold[848 + g*16 + (q)]; \
    yy = mishf(yy); y_##q = ((q) < numv) ? yy : 0.f; }
    REP16_0(BN1)
#undef BN1

    float z0 = 0.f, z1 = 0.f;
#define BF2(p) z0 += y_##p * W2g[g*32 + (p)]; z1 += y_##p * W2g[g*32 + 16 + (p)];
    REP16_0(BF2)
#undef BF2
    z0 = mishf(z0 * fold[1104 + g*2 + 0] + fold[1136 + g*2 + 0]);
    z1 = mishf(z1 * fold[1104 + g*2 + 1] + fold[1136 + g*2 + 1]);

    int k0 = ii*32 + g*2;
    *(float2*)(x17g + aidx*128 + k0) = make_float2(z0, z1);
}

// ---------------- bfe3 fused: x19 compactly back into x17g ----------------
__global__ __launch_bounds__(512, 4) void bfe3_fused(
    const int* __restrict__ nactp,
    const float* __restrict__ W3, const float* __restrict__ fold,
    float* __restrict__ x17g)
{
    __shared__ float XL[64*128];
    int tid = threadIdx.x;
    int n_act = *nactp;
    int cb = blockIdx.x * 64;

    for (int i = tid; i < 64*32; i += 512) {
        int c = i >> 5, kc = i & 31;
        float4 val = (cb + c < n_act) ? ((const float4*)x17g)[(size_t)(cb+c)*32 + kc]
                                      : make_float4(0.f,0.f,0.f,0.f);
        ((float4*)XL)[c*32 + (kc ^ (c & 31))] = val;
    }
    __syncthreads();

    int wv = __builtin_amdgcn_readfirstlane(tid >> 6);
    int c  = tid & 63;
    int ob = wv * 16;
    int cswz = c & 31;
    const float4* xrow = (const float4*)XL + c*32;
    const float4* W4p = (const float4*)W3;

#define DECLB(q) f32x2 ap_##q = {0.f, 0.f};
#define ACCB(q) { const f32x2* wp_ = (const f32x2*)(W4p + (ob+(q))*32 + kc); \
    ap_##q += xv01 * wp_[0]; ap_##q += xv23 * wp_[1]; }
#define ACTB(q) float a_##q; { float yy = (ap_##q.x + ap_##q.y) * fold[336+ob+(q)] + fold[464+ob+(q)]; a_##q = mishf(yy); }
    {
        REP16_0(DECLB)
        for (int kc = 0; kc < 32; kc++) {
            float4 xv = xrow[kc ^ cswz];
            f32x2 xv01 = {xv.x, xv.y}, xv23 = {xv.z, xv.w};
            REP16_0(ACCB)
        }
        REP16_0(ACTB)
        __syncthreads();
        ((float4*)XL)[c*32 + ((wv*4 + 0) ^ cswz)] = make_float4(a_0,  a_1,  a_2,  a_3);
        ((float4*)XL)[c*32 + ((wv*4 + 1) ^ cswz)] = make_float4(a_4,  a_5,  a_6,  a_7);
        ((float4*)XL)[c*32 + ((wv*4 + 2) ^ cswz)] = make_float4(a_8,  a_9,  a_10, a_11);
        ((float4*)XL)[c*32 + ((wv*4 + 3) ^ cswz)] = make_float4(a_12, a_13, a_14, a_15);
    }
    __syncthreads();

    {
        const float4* yrow = (const float4*)XL + c*32;
        REP16_0(DECLB)
        for (int kc = 0; kc < 32; kc++) {
            float4 xv = yrow[kc ^ cswz];
            f32x2 xv01 = {xv.x, xv.y}, xv23 = {xv.z, xv.w};
            REP16_0(ACCB)
        }
        REP16_0(ACTB)
        float4* dst = (float4*)(x17g + (size_t)(cb + c)*128 + ob);
        dst[0] = make_float4(a_0,  a_1,  a_2,  a_3);
        dst[1] = make_float4(a_4,  a_5,  a_6,  a_7);
        dst[2] = make_float4(a_8,  a_9,  a_10, a_11);
        dst[3] = make_float4(a_12, a_13, a_14, a_15);
    }
#undef DECLB
#undef ACCB
#undef ACTB
}

// ---------------- bev_write: tiled transpose-scatter (replaces out memset) ----------------
__global__ __launch_bounds__(512, 2) void bev_write(
    const int* __restrict__ idx, const float* __restrict__ x19c,
    float* __restrict__ out)
{
    __shared__ float XT[128*65];
    int bid = blockIdx.x;
    int cx = bid % BEVW;
    int cy0 = (bid / BEVW) << 6;
    int tid = threadIdx.x;

    int cell_l = tid >> 3;
    int chq = (tid & 7) << 4;
    int cy = cy0 + cell_l;
    float4 v0 = make_float4(0.f,0.f,0.f,0.f), v1 = v0, v2 = v0, v3 = v0;
    if (cy < BEVH) {
        int ai = idx[cy*BEVW + cx];
        if (ai >= 0) {
            const float4* src = (const float4*)(x19c + (size_t)ai*128 + chq);
            v0 = src[0]; v1 = src[1]; v2 = src[2]; v3 = src[3];
        }
    }
    float* d = XT + chq*65 + cell_l;
    d[0*65]=v0.x;  d[1*65]=v0.y;  d[2*65]=v0.z;  d[3*65]=v0.w;
    d[4*65]=v1.x;  d[5*65]=v1.y;  d[6*65]=v1.z;  d[7*65]=v1.w;
    d[8*65]=v2.x;  d[9*65]=v2.y;  d[10*65]=v2.z; d[11*65]=v2.w;
    d[12*65]=v3.x; d[13*65]=v3.y; d[14*65]=v3.z; d[15*65]=v3.w;
    __syncthreads();

    int wv2 = tid >> 6, lane = tid & 63;
    int cyw = cy0 + lane;
    if (cyw < BEVH) {
        float* op = out + cx*BEVH + cyw;
#pragma unroll
        for (int k = 0; k < 16; k++) {
            int c = (wv2 << 4) + k;
            op[(size_t)c*NCELL] = XT[c*65 + lane];
        }
    }
}

extern "C" void kernel_launch(void* const* d_in, const int* in_sizes, int n_in,
                              void* d_out, int out_size, void* d_ws, size_t ws_size,
                              hipStream_t stream) {
    const float* features = (const float*)d_in[0];
    const int*   coors    = (const int*)d_in[1];
    const int*   num_vox  = (const int*)d_in[2];
    const float* vfe1_W   = (const float*)d_in[3];
    const float* vfe1_bn  = (const float*)d_in[4];
    const float* vfe2_W   = (const float*)d_in[5];
    const float* vfe2_bn  = (const float*)d_in[6];
    const float* vfe3_W   = (const float*)d_in[7];
    const float* vfe3_bn  = (const float*)d_in[8];
    const float* vfe4_W   = (const float*)d_in[9];
    const float* vfe4_bn  = (const float*)d_in[10];
    const float* bfe1_W   = (const float*)d_in[11];
    const float* bfe1_bn  = (const float*)d_in[12];
    const float* bfe2_W   = (const float*)d_in[13];
    const float* bfe2_bn  = (const float*)d_in[14];
    const float* bfe3_W   = (const float*)d_in[15];
    const float* bfe3_bn  = (const float*)d_in[16];
    float* out = (float*)d_out;

    char* ws = (char*)d_ws;
    int*    nact      = (int*)ws;
    int*    cnt       = (int*)(ws + 256);
    int*    list      = (int*)(ws + 857600);
    float*  voxelwise = (float*)(ws + 14571008);
    int*    act       = (int*)(ws + 24811008);
    float*  x17g      = (float*)(ws + 24971008);
    float*  fold      = (float*)(ws + 45451008);
    ushort* w4fh      = (ushort*)(ws + 45455680);
    ushort* w4fl      = (ushort*)(ws + 45463872);
    int*    idx       = (int*)(ws + 45472064);
    ushort* w3fh      = (ushort*)(ws + 46329344);
    ushort* w3fl      = (ushort*)(ws + 46337536);

    (void)hipMemsetAsync(ws, 0, 857600, stream);               // nact + cnt
    (void)hipMemsetAsync(idx, 0xFF, (size_t)NCELL*4, stream);  // idx = -1

    setup_kernel<<<1, 256, 0, stream>>>(vfe1_bn, vfe2_bn, vfe3_bn, vfe4_bn,
                                        bfe1_bn, bfe2_bn, bfe3_bn, vfe4_W, vfe3_W,
                                        fold, w4fh, w4fl, w3fh, w3fl);
    vfe_kernel<<<NVOX/8, 256, 0, stream>>>(features, coors, num_vox,
                                           vfe1_W, vfe2_W, w3fh, w3fl, w4fh, w4fl, fold,
                                           voxelwise, cnt, list, nact, act);
    bfe_front<<<NVOX/4, 256, 0, stream>>>(nact, act, cnt, list, voxelwise,
                                          bfe1_W, bfe2_W, fold, x17g, idx);
    bfe3_fused<<<(NVOX+63)/64, 512, 0, stream>>>(nact, bfe3_W, fold, x17g);
    bev_write<<<BEVW*8, 512, 0, stream>>>(idx, x17g, out);
}

// Round 14
// 525.603 us; speedup vs baseline: 1.2357x; 1.0000x over previous
//
#include <hip/hip_runtime.h>

#define BEVW 432
#define BEVH 496
#define NCELL (BEVW*BEVH)      // 214272
#define NVOX  40000
#define EPSB  1e-5f

typedef float f32x2 __attribute__((ext_vector_type(2)));
typedef float f32x4 __attribute__((ext_vector_type(4)));
typedef unsigned int u32x4 __attribute__((ext_vector_type(4)));
typedef short bf16x8 __attribute__((ext_vector_type(8)));

// ---- repeat macros ----
#define REP8_0(M)  M(0) M(1) M(2) M(3) M(4) M(5) M(6) M(7)
#define REP8_8(M)  M(8) M(9) M(10) M(11) M(12) M(13) M(14) M(15)
#define REP8_16(M) M(16) M(17) M(18) M(19) M(20) M(21) M(22) M(23)
#define REP8_24(M) M(24) M(25) M(26) M(27) M(28) M(29) M(30) M(31)
#define REP16_0(M)  REP8_0(M)  REP8_8(M)
#define REP32_0(M) REP16_0(M) REP8_16(M) REP8_24(M)

// ---------------- workspace layout (bytes) ----------------
// 0        : int nact (zeroed)
// 256      : int cnt[NCELL]  (zeroed)            -> 857344
// 857344   : int idx[NCELL]  (zeroed; aidx+1)    -> 1714432
// 1714432  : int list[NCELL*16]                  -> 15427840
// 15427840 : float voxelwise[NVOX*64]            -> 25667840
// 25667840 : int act[NVOX]                       -> 25827840
// 25827840 : float x17g[NVOX*128] (x17 then x19) -> 46307840
// 46307840 : float fold[1168]
// 46312512 : ushort w4fh[4096] | 46320704: w4fl | 46337088... w3fh@46328896 w3fl@46337088

__device__ __forceinline__ float mishf(float y) {
    float e = __expf(fminf(y, 40.f));
    float n = e * (e + 2.f);
    return y * n * __builtin_amdgcn_rcpf(n + 2.f);
}

template <int CTRL>
__device__ __forceinline__ float dppmaxf(float a) {
    int p = __builtin_amdgcn_update_dpp(0, __float_as_int(a), CTRL, 0xF, 0xF, true);
    return fmaxf(a, __int_as_float(p));
}
#define WMAX32(a) { \
    a = dppmaxf<0xB1>(a); \
    a = dppmaxf<0x4E>(a); \
    a = dppmaxf<0x141>(a); \
    a = dppmaxf<0x140>(a); \
    a = fmaxf(a, __int_as_float(__builtin_amdgcn_ds_swizzle(__float_as_int(a), 0x401F))); }

__device__ __forceinline__ bf16x8 mkbf8(uint a, uint b, uint c, uint d) {
    u32x4 t = {a, b, c, d};
    return __builtin_bit_cast(bf16x8, t);
}

// split fp32 -> (hi bf16 | lo bf16 << 16). Hi = TRUNCATION (1 op); lo = x - hi is
// then exact in fp32, RNE'd to bf16. Combined representation err ~2^-17 rel.
__device__ __forceinline__ uint splitbf(float x) {
    uint rh = __float_as_uint(x) & 0xFFFF0000u;
    float lof = x - __uint_as_float(rh);
    uint ul = __float_as_uint(lof);
    uint rl = (ul + 0x7FFFu + ((ul >> 16) & 1u)) >> 16;
    return (rh >> 16) | (rl << 16);
}

// fold layout: vfe1 s@0 t@8 | vfe2 s@16 t@48 | vfe3 s@80 t@144 | vfe4 s@208 t@272
// bfe3 s@336 t@464 | bfe1 s@592 t@848 | bfe2 s@1104 t@1136
__global__ __launch_bounds__(256) void setup_kernel(
    const float* __restrict__ vbn1, const float* __restrict__ vbn2,
    const float* __restrict__ vbn3, const float* __restrict__ vbn4,
    const float* __restrict__ bbn1, const float* __restrict__ bbn2,
    const float* __restrict__ bbn3, const float* __restrict__ W4,
    const float* __restrict__ W3g,
    float* __restrict__ fold, ushort* __restrict__ w4fh, ushort* __restrict__ w4fl,
    ushort* __restrict__ w3fh, ushort* __restrict__ w3fl)
{
    int tid = threadIdx.x;
    if (tid < 8)  { float s = vbn1[tid]/sqrtf(vbn1[24+tid]+EPSB);  fold[tid]      = s; fold[8+tid]   = vbn1[8+tid]  - vbn1[16+tid]*s; }
    if (tid < 32) { float s = vbn2[tid]/sqrtf(vbn2[96+tid]+EPSB);  fold[16+tid]   = s; fold[48+tid]  = vbn2[32+tid] - vbn2[64+tid]*s; }
    if (tid < 64) { float s = vbn3[tid]/sqrtf(vbn3[192+tid]+EPSB); fold[80+tid]   = s; fold[144+tid] = vbn3[64+tid] - vbn3[128+tid]*s; }
    if (tid < 64) { float s = vbn4[tid]/sqrtf(vbn4[192+tid]+EPSB); fold[208+tid]  = s; fold[272+tid] = vbn4[64+tid] - vbn4[128+tid]*s; }
    if (tid < 128){ float s = bbn3[tid]/sqrtf(bbn3[384+tid]+EPSB); fold[336+tid]  = s; fold[464+tid] = bbn3[128+tid]- bbn3[256+tid]*s; }
    { int g = tid >> 4, q = tid & 15;
      const float* b = bbn1 + g*64;
      float s = b[q]/sqrtf(b[48+q]+EPSB);
      fold[592+tid] = s; fold[848+tid] = b[16+q] - b[32+q]*s; }
    if (tid < 32) { int g = tid >> 1, c = tid & 1;
      const float* b = bbn2 + g*8;
      float s = b[c]/sqrtf(b[6+c]+EPSB);
      fold[1104+tid] = s; fold[1136+tid] = b[2+c] - b[4+c]*s; }

    // B-fragments (B[k][n] = W[n][k]) split bf16 hi/lo, for W4^T and W3^T.
    // frag idx = ((kc*4 + nt)*64 + lane)*8 + j ; n = (lane&15)+16nt ; k = kc*32 + (lane>>4)*8 + j
    for (int i = tid; i < 4096; i += 256) {
        int j = i & 7, ln = (i >> 3) & 63, nt = (i >> 9) & 3, kc = i >> 11;
        int n = (ln & 15) + nt*16;
        int k = kc*32 + (ln >> 4)*8 + j;
        {
            float val = W4[n*64 + k];
            uint rh = __float_as_uint(val) & 0xFFFF0000u;
            float lof = val - __uint_as_float(rh);
            uint ul = __float_as_uint(lof);
            uint rl = (ul + 0x7FFFu + ((ul >> 16) & 1u)) >> 16;
            w4fh[i] = (ushort)(rh >> 16);
            w4fl[i] = (ushort)rl;
        }
        {
            float val = W3g[n*64 + k];
            uint rh = __float_as_uint(val) & 0xFFFF0000u;
            float lof = val - __uint_as_float(rh);
            uint ul = __float_as_uint(lof);
            uint rl = (ul + 0x7FFFu + ((ul >> 16) & 1u)) >> 16;
            w3fh[i] = (ushort)(rh >> 16);
            w3fl[i] = (ushort)rl;
        }
    }
}

// pair list
#define PAIRS(M) M(0,0,1) M(1,2,3) M(2,4,5) M(3,6,7) M(4,8,9) M(5,10,11) \
  M(6,12,13) M(7,14,15) M(8,16,17) M(9,18,19) M(10,20,21) M(11,22,23) \
  M(12,24,25) M(13,26,27) M(14,28,29) M(15,30,31)

#define MF3(D, AH, AL, BH, BL) \
    D = __builtin_amdgcn_mfma_f32_16x16x32_bf16(AL, BH, D, 0, 0, 0); \
    D = __builtin_amdgcn_mfma_f32_16x16x32_bf16(AH, BL, D, 0, 0, 0); \
    D = __builtin_amdgcn_mfma_f32_16x16x32_bf16(AH, BH, D, 0, 0, 0);

// A-tile group: A frags from LDS rows (stride 33), 4 B frags from L1, 12 MFMAs.
#define DOMTX(SRCP, BHP, BLP, mt, D0, D1, D2, D3) { \
    const uint* ap_ = (SRCP) + ((lane & 15) + 16*(mt))*33 + quad*8; \
    uint u0 = ap_[0], u1 = ap_[1], u2 = ap_[2], u3 = ap_[3]; \
    uint u4 = ap_[4], u5 = ap_[5], u6 = ap_[6], u7 = ap_[7]; \
    bf16x8 Ah = mkbf8(__builtin_amdgcn_perm(u1,u0,0x05040100), __builtin_amdgcn_perm(u3,u2,0x05040100), \
                      __builtin_amdgcn_perm(u5,u4,0x05040100), __builtin_amdgcn_perm(u7,u6,0x05040100)); \
    bf16x8 Al = mkbf8(__builtin_amdgcn_perm(u1,u0,0x07060302), __builtin_amdgcn_perm(u3,u2,0x07060302), \
                      __builtin_amdgcn_perm(u5,u4,0x07060302), __builtin_amdgcn_perm(u7,u6,0x07060302)); \
    { uint4 h = (BHP)[0];   uint4 l = (BLP)[0];   bf16x8 Bh = mkbf8(h.x,h.y,h.z,h.w), Bl = mkbf8(l.x,l.y,l.z,l.w); MF3(D0, Ah, Al, Bh, Bl) } \
    { uint4 h = (BHP)[64];  uint4 l = (BLP)[64];  bf16x8 Bh = mkbf8(h.x,h.y,h.z,h.w), Bl = mkbf8(l.x,l.y,l.z,l.w); MF3(D1, Ah, Al, Bh, Bl) } \
    { uint4 h = (BHP)[128]; uint4 l = (BLP)[128]; bf16x8 Bh = mkbf8(h.x,h.y,h.z,h.w), Bl = mkbf8(l.x,l.y,l.z,l.w); MF3(D2, Ah, Al, Bh, Bl) } \
    { uint4 h = (BHP)[192]; uint4 l = (BLP)[192]; bf16x8 Bh = mkbf8(h.x,h.y,h.z,h.w), Bl = mkbf8(l.x,l.y,l.z,l.w); MF3(D3, Ah, Al, Bh, Bl) } }

// ---------------- VFE: single-wave blocks (2 voxels/wave), fe3+fe4 on MFMA ----------------
// Block = 64 threads = 1 wave -> LDS allocation is wave-granular: 163840/17152 = 9
// waves/CU (vs 8 at 256-thr blocks). No __syncthreads needed (all LDS wave-private,
// DS ops in-order per wave). (64,3): 170-reg budget, known spill-free (r11/r13).
__global__ __launch_bounds__(64, 3) void vfe_kernel(
    const float* __restrict__ feat, const int* __restrict__ coors,
    const int* __restrict__ nvx,
    const float* __restrict__ W1, const float* __restrict__ W2,
    const ushort* __restrict__ w3fh, const ushort* __restrict__ w3fl,
    const ushort* __restrict__ w4fh, const ushort* __restrict__ w4fl,
    const float* __restrict__ fold,
    float* __restrict__ voxelwise, int* __restrict__ cnt,
    int* __restrict__ list, int* __restrict__ nact, int* __restrict__ act)
{
    __shared__ char ldsbuf[17152];   // x2s[2][64][33] u32 + aggL[64] f32
    int tid = threadIdx.x;
    int lane = tid;
    int quad = lane >> 4;
    int v = blockIdx.x * 2 + (tid >> 5);
    int vA = blockIdx.x * 2;
    int t = tid & 31;
    uint*  x2s  = (uint*)ldsbuf;
    float* aggL = (float*)(ldsbuf + 16896);

    const float* fp = feat + (v*32 + t)*8;
    float4 fa = *(const float4*)fp;
    float4 fb = *(const float4*)(fp+4);
    int numv = nvx[v];
    float maskf = (t < numv) ? 1.f : 0.f;

    // ---- fe1 (8->8) + pool ----
#define D1(o) float x1_##o; float m1_##o;
    REP8_0(D1)
#undef D1
#define FE1(o) { const float* w = W1 + (o)*8; \
    float ya = fa.x*w[0] + fa.y*w[1]; float yb = fa.z*w[2] + fa.w*w[3]; \
    float yc = fb.x*w[4] + fb.y*w[5]; float yd = fb.z*w[6] + fb.w*w[7]; \
    float yy = ((ya+yb)+(yc+yd)) * fold[(o)] + fold[8+(o)]; \
    x1_##o = mishf(yy); }
    REP8_0(FE1)
#undef FE1
#define P1(o) { float a = x1_##o; WMAX32(a); m1_##o = a; }
    REP8_0(P1)
#undef P1

    f32x2 x1p_0 = {x1_0,x1_1}, x1p_1 = {x1_2,x1_3}, x1p_2 = {x1_4,x1_5}, x1p_3 = {x1_6,x1_7};
    f32x2 m1p_0 = {m1_0,m1_1}, m1p_1 = {m1_2,m1_3}, m1p_2 = {m1_4,m1_5}, m1p_3 = {m1_6,m1_7};

    // ---- fe2 (16->32) + pool ----
#define D2(o) float x2_##o; float agg_##o;
    REP32_0(D2)
#undef D2
#define FE2(o) { const f32x2* wp = (const f32x2*)(W2 + (o)*16); \
    f32x2 sa = x1p_0*wp[0]; sa += x1p_1*wp[1]; \
    f32x2 sb = x1p_2*wp[2]; sb += x1p_3*wp[3]; \
    f32x2 sc = m1p_0*wp[4]; sc += m1p_1*wp[5]; \
    f32x2 sd = m1p_2*wp[6]; sd += m1p_3*wp[7]; \
    sa += sb; sc += sd; sa += sc; \
    float yy = (sa.x + sa.y) * fold[16+(o)] + fold[48+(o)]; \
    x2_##o = mishf(yy); }
    REP32_0(FE2)
#undef FE2
#define P2(o) { float a = x2_##o; WMAX32(a); agg_##o = a; }
    REP32_0(P2)
#undef P2

#define PX(i,a,b) f32x2 x2p_##i = {x2_##a, x2_##b}; f32x2 aggp_##i = {agg_##a, agg_##b};
    PAIRS(PX)
#undef PX

    f32x2 maskp = {maskf, maskf};
#define MSK(i) x2p_##i *= maskp; aggp_##i *= maskp;
    REP16_0(MSK)
#undef MSK

    // aggL: exact fp32 agg (lane t==0 always valid -> masked == unmasked)
    if (t == 0) {
        float* ag = aggL + (lane >> 5)*32;
#define AGW(i) ag[2*(i)] = aggp_##i.x; ag[2*(i)+1] = aggp_##i.y;
        REP16_0(AGW)
#undef AGW
    }

    int nA = __shfl(numv, 0);
    int nB = __shfl(numv, 32);

    // ---- stage masked x2 split into LDS: chunk0 = ch 0..31, chunk1 = ch 32..63 ----
#define X2W(i) { \
    x2s[lane*33 + 2*(i)]          = splitbf(x2p_##i.x); \
    x2s[lane*33 + 2*(i)+1]        = splitbf(x2p_##i.y); \
    x2s[2112 + lane*33 + 2*(i)]   = splitbf(aggp_##i.x); \
    x2s[2112 + lane*33 + 2*(i)+1] = splitbf(aggp_##i.y); }
    REP16_0(X2W)
#undef X2W

    // ---- fe3: 96 MFMAs over K=64 ----
#define E_DECL(i) f32x4 e_##i = {0.f,0.f,0.f,0.f};
    REP16_0(E_DECL)
#undef E_DECL
    {
        const uint4* bh3 = (const uint4*)w3fh + lane;
        const uint4* bl3 = (const uint4*)w3fl + lane;
        DOMTX(x2s, bh3, bl3, 0, e_0, e_1, e_2, e_3)
        DOMTX(x2s, bh3, bl3, 1, e_4, e_5, e_6, e_7)
        DOMTX(x2s, bh3, bl3, 2, e_8, e_9, e_10, e_11)
        DOMTX(x2s, bh3, bl3, 3, e_12, e_13, e_14, e_15)
    }
    {
        const uint4* bh3 = (const uint4*)w3fh + 256 + lane;
        const uint4* bl3 = (const uint4*)w3fl + 256 + lane;
        const uint* sp = x2s + 2112;
        DOMTX(sp, bh3, bl3, 0, e_0, e_1, e_2, e_3)
        DOMTX(sp, bh3, bl3, 1, e_4, e_5, e_6, e_7)
        DOMTX(sp, bh3, bl3, 2, e_8, e_9, e_10, e_11)
        DOMTX(sp, bh3, bl3, 3, e_12, e_13, e_14, e_15)
    }

    // ---- fe3 epilogue (bn+mish+split, C-layout) interleaved with fe4 MFMA ----
    int c0 = lane & 15;
    uint* x3st = x2s + 2112;   // agg chunk reused as x3 staging
#define DD(i) f32x4 d_##i = {0.f,0.f,0.f,0.f};
    REP16_0(DD)
#undef DD

#define POST(TI, mt, nt) { \
    float s_ = fold[80 + c0 + 16*(nt)], tb_ = fold[144 + c0 + 16*(nt)]; \
    int col_ = c0 + 16*((nt)&1); \
    int rowb_ = quad*4 + 16*(mt); \
    x3st[(rowb_+0)*33 + col_] = splitbf(mishf(e_##TI.x * s_ + tb_)); \
    x3st[(rowb_+1)*33 + col_] = splitbf(mishf(e_##TI.y * s_ + tb_)); \
    x3st[(rowb_+2)*33 + col_] = splitbf(mishf(e_##TI.z * s_ + tb_)); \
    x3st[(rowb_+3)*33 + col_] = splitbf(mishf(e_##TI.w * s_ + tb_)); }

    { // output chunk 0: fe3 outputs 0..31 (nt 0,1)
        POST(0,0,0)  POST(1,0,1)
        POST(4,1,0)  POST(5,1,1)
        POST(8,2,0)  POST(9,2,1)
        POST(12,3,0) POST(13,3,1)
        const uint4* bh4 = (const uint4*)w4fh + lane;
        const uint4* bl4 = (const uint4*)w4fl + lane;
        DOMTX(x3st, bh4, bl4, 0, d_0, d_1, d_2, d_3)
        DOMTX(x3st, bh4, bl4, 1, d_4, d_5, d_6, d_7)
        DOMTX(x3st, bh4, bl4, 2, d_8, d_9, d_10, d_11)
        DOMTX(x3st, bh4, bl4, 3, d_12, d_13, d_14, d_15)
    }
    { // output chunk 1: fe3 outputs 32..63 (nt 2,3)
        POST(2,0,2)  POST(3,0,3)
        POST(6,1,2)  POST(7,1,3)
        POST(10,2,2) POST(11,2,3)
        POST(14,3,2) POST(15,3,3)
        const uint4* bh4 = (const uint4*)w4fh + 256 + lane;
        const uint4* bl4 = (const uint4*)w4fl + 256 + lane;
        DOMTX(x3st, bh4, bl4, 0, d_0, d_1, d_2, d_3)
        DOMTX(x3st, bh4, bl4, 1, d_4, d_5, d_6, d_7)
        DOMTX(x3st, bh4, bl4, 2, d_8, d_9, d_10, d_11)
        DOMTX(x3st, bh4, bl4, 3, d_12, d_13, d_14, d_15)
    }
#undef POST

    // ---- bn4 + mish + residual + pool in C layout ----
    float s0f = fold[208+c0],    t0f = fold[272+c0];
    float s1f = fold[208+16+c0], t1f = fold[272+16+c0];
    float s2f = fold[208+32+c0], t2f = fold[272+32+c0];
    float s3f = fold[208+48+c0], t3f = fold[272+48+c0];
    float rA2 = aggL[c0],      rA3 = aggL[16+c0];
    float rB2 = aggL[32+c0],   rB3 = aggL[48+c0];
    float pA0=-3.4e38f, pA1=-3.4e38f, pA2=-3.4e38f, pA3=-3.4e38f;
    float pB0=-3.4e38f, pB1=-3.4e38f, pB2=-3.4e38f, pB3=-3.4e38f;

#define RECON(u) (__uint_as_float((u)<<16) + __uint_as_float((u) & 0xFFFF0000u))
#define FTP(D, mt, nt, SS, TT, PV) { \
    int nv = ((mt) >> 1) ? nB : nA; \
    int rf = quad*4 + 16*(mt); \
    int rt = quad*4 + 16*((mt)&1); \
    int cb = c0 + 16*(nt); \
    float m0=(rt+0<nv)?1.f:0.f, m1=(rt+1<nv)?1.f:0.f, m2=(rt+2<nv)?1.f:0.f, m3=(rt+3<nv)?1.f:0.f; \
    uint ua_ = x2s[(rf+0)*33 + cb], ub_ = x2s[(rf+1)*33 + cb]; \
    uint uc_ = x2s[(rf+2)*33 + cb], ud_ = x2s[(rf+3)*33 + cb]; \
    float y0 = mishf(D.x*SS + TT)*m0 + RECON(ua_); \
    float y1 = mishf(D.y*SS + TT)*m1 + RECON(ub_); \
    float y2 = mishf(D.z*SS + TT)*m2 + RECON(uc_); \
    float y3 = mishf(D.w*SS + TT)*m3 + RECON(ud_); \
    PV = fmaxf(PV, fmaxf(fmaxf(y0,y1), fmaxf(y2,y3))); }

#define FTA(D, mt, nt, SS, TT, AG, PV) { \
    int nv = ((mt) >> 1) ? nB : nA; \
    int rt = quad*4 + 16*((mt)&1); \
    float m0=(rt+0<nv)?1.f:0.f, m1=(rt+1<nv)?1.f:0.f, m2=(rt+2<nv)?1.f:0.f, m3=(rt+3<nv)?1.f:0.f; \
    float y0 = (mishf(D.x*SS + TT) + AG)*m0; \
    float y1 = (mishf(D.y*SS + TT) + AG)*m1; \
    float y2 = (mishf(D.z*SS + TT) + AG)*m2; \
    float y3 = (mishf(D.w*SS + TT) + AG)*m3; \
    PV = fmaxf(PV, fmaxf(fmaxf(y0,y1), fmaxf(y2,y3))); }

    FTP(d_0, 0, 0, s0f, t0f, pA0)  FTP(d_1, 0, 1, s1f, t1f, pA1)
    FTA(d_2, 0, 2, s2f, t2f, rA2, pA2)  FTA(d_3, 0, 3, s3f, t3f, rA3, pA3)
    FTP(d_4, 1, 0, s0f, t0f, pA0)  FTP(d_5, 1, 1, s1f, t1f, pA1)
    FTA(d_6, 1, 2, s2f, t2f, rA2, pA2)  FTA(d_7, 1, 3, s3f, t3f, rA3, pA3)
    FTP(d_8, 2, 0, s0f, t0f, pB0)  FTP(d_9, 2, 1, s1f, t1f, pB1)
    FTA(d_10, 2, 2, s2f, t2f, rB2, pB2)  FTA(d_11, 2, 3, s3f, t3f, rB3, pB3)
    FTP(d_12, 3, 0, s0f, t0f, pB0)  FTP(d_13, 3, 1, s1f, t1f, pB1)
    FTA(d_14, 3, 2, s2f, t2f, rB2, pB2)  FTA(d_15, 3, 3, s3f, t3f, rB3, pB3)
#undef FTP
#undef FTA
#undef RECON

#define RED(p) p = fmaxf(p, __shfl_xor(p, 16)); p = fmaxf(p, __shfl_xor(p, 32));
    RED(pA0) RED(pA1) RED(pA2) RED(pA3) RED(pB0) RED(pB1) RED(pB2) RED(pB3)
#undef RED

    if (quad == 0) {
        float* vwA = voxelwise + vA*64;
        vwA[c0] = pA0; vwA[c0+16] = pA1; vwA[c0+32] = pA2; vwA[c0+48] = pA3;
        float* vwB = voxelwise + (vA+1)*64;
        vwB[c0] = pB0; vwB[c0+16] = pB1; vwB[c0+32] = pB2; vwB[c0+48] = pB3;
    }

    if (t == 0) {
        int cell = coors[v*2] * BEVW + coors[v*2+1];
        int pos = atomicAdd(&cnt[cell], 1);
        if (pos < 16) list[cell*16 + pos] = v;
        if (pos == 0) { int k = atomicAdd(nact, 1); act[k] = cell; }
    }
}

// ---------------- BFE front: 1 wave = 1 cell; records idx[cell]=aidx+1 ----------------
__global__ __launch_bounds__(256) void bfe_front(
    const int* __restrict__ nact, const int* __restrict__ act,
    const int* __restrict__ cnt, const int* __restrict__ list,
    const float* __restrict__ voxelwise,
    const float* __restrict__ W1g, const float* __restrict__ W2g,
    const float* __restrict__ fold, float* __restrict__ x17g,
    int* __restrict__ idx)
{
    int n_act = *nact;
    int aidx = blockIdx.x * 4 + (threadIdx.x >> 6);
    if (aidx >= n_act) return;

    int lane = threadIdx.x & 63;
    int g = lane >> 2, ii = lane & 3;
    int cell = act[aidx];
    int numv = min(cnt[cell], 16);
    if (lane == 0) idx[cell] = aidx + 1;

    int myidx = (lane < numv) ? list[cell*16 + lane] : (0x40000000 + lane);
    int rank = 0;
    for (int j = 0; j < numv; j++) { int vj = __shfl(myidx, j); rank += (vj < myidx) ? 1 : 0; }
    if (lane >= numv) rank = lane;
    int sorted = __builtin_amdgcn_ds_permute(rank << 2, myidx);

#define YD(q) float y_##q = 0.f;
    REP16_0(YD)
#undef YD
    for (int p = 0; p < numv; p++) {
        int sv = __shfl(sorted, p);
        float val = voxelwise[sv*64 + lane];
        const float* w = W1g + g*256 + p;
#define BF1(q) y_##q += val * w[(q)*16];
        REP16_0(BF1)
#undef BF1
    }
#define BN1(q) { float yy = y_##q * fold[592 + g*16 + (q)] + fold[848 + g*16 + (q)]; \
    yy = mishf(yy); y_##q = ((q) < numv) ? yy : 0.f; }
    REP16_0(BN1)
#undef BN1

    float z0 = 0.f, z1 = 0.f;
#define BF2(p) z0 += y_##p * W2g[g*32 + (p)]; z1 += y_##p * W2g[g*32 + 16 + (p)];
    REP16_0(BF2)
#undef BF2
    z0 = mishf(z0 * fold[1104 + g*2 + 0] + fold[1136 + g*2 + 0]);
    z1 = mishf(z1 * fold[1104 + g*2 + 1] + fold[1136 + g*2 + 1]);

    int k0 = ii*32 + g*2;
    *(float2*)(x17g + aidx*128 + k0) = make_float2(z0, z1);
}

// ---------------- bfe3 fused: x19 compactly back into x17g ----------------
__global__ __launch_bounds__(512, 4) void bfe3_fused(
    const int* __restrict__ nactp,
    const float* __restrict__ W3, const float* __restrict__ fold,
    float* __restrict__ x17g)
{
    __shared__ float XL[64*128];
    int tid = threadIdx.x;
    int n_act = *nactp;
    int cb = blockIdx.x * 64;

    for (int i = tid; i < 64*32; i += 512) {
        int c = i >> 5, kc = i & 31;
        float4 val = (cb + c < n_act) ? ((const float4*)x17g)[(size_t)(cb+c)*32 + kc]
                                      : make_float4(0.f,0.f,0.f,0.f);
        ((float4*)XL)[c*32 + (kc ^ (c & 31))] = val;
    }
    __syncthreads();

    int wv = __builtin_amdgcn_readfirstlane(tid >> 6);
    int c  = tid & 63;
    int ob = wv * 16;
    int cswz = c & 31;
    const float4* xrow = (const float4*)XL + c*32;
    const float4* W4p = (const float4*)W3;

#define DECLB(q) f32x2 ap_##q = {0.f, 0.f};
#define ACCB(q) { const f32x2* wp_ = (const f32x2*)(W4p + (ob+(q))*32 + kc); \
    ap_##q += xv01 * wp_[0]; ap_##q += xv23 * wp_[1]; }
#define ACTB(q) float a_##q; { float yy = (ap_##q.x + ap_##q.y) * fold[336+ob+(q)] + fold[464+ob+(q)]; a_##q = mishf(yy); }
    {
        REP16_0(DECLB)
        for (int kc = 0; kc < 32; kc++) {
            float4 xv = xrow[kc ^ cswz];
            f32x2 xv01 = {xv.x, xv.y}, xv23 = {xv.z, xv.w};
            REP16_0(ACCB)
        }
        REP16_0(ACTB)
        __syncthreads();
        ((float4*)XL)[c*32 + ((wv*4 + 0) ^ cswz)] = make_float4(a_0,  a_1,  a_2,  a_3);
        ((float4*)XL)[c*32 + ((wv*4 + 1) ^ cswz)] = make_float4(a_4,  a_5,  a_6,  a_7);
        ((float4*)XL)[c*32 + ((wv*4 + 2) ^ cswz)] = make_float4(a_8,  a_9,  a_10, a_11);
        ((float4*)XL)[c*32 + ((wv*4 + 3) ^ cswz)] = make_float4(a_12, a_13, a_14, a_15);
    }
    __syncthreads();

    {
        const float4* yrow = (const float4*)XL + c*32;
        REP16_0(DECLB)
        for (int kc = 0; kc < 32; kc++) {
            float4 xv = yrow[kc ^ cswz];
            f32x2 xv01 = {xv.x, xv.y}, xv23 = {xv.z, xv.w};
            REP16_0(ACCB)
        }
        REP16_0(ACTB)
        float4* dst = (float4*)(x17g + (size_t)(cb + c)*128 + ob);
        dst[0] = make_float4(a_0,  a_1,  a_2,  a_3);
        dst[1] = make_float4(a_4,  a_5,  a_6,  a_7);
        dst[2] = make_float4(a_8,  a_9,  a_10, a_11);
        dst[3] = make_float4(a_12, a_13, a_14, a_15);
    }
#undef DECLB
#undef ACCB
#undef ACTB
}

// ---------------- bev_write: tiled transpose-scatter (replaces out memset) ----------------
__global__ __launch_bounds__(512, 2) void bev_write(
    const int* __restrict__ idx, const float* __restrict__ x19c,
    float* __restrict__ out)
{
    __shared__ float XT[128*65];
    int bid = blockIdx.x;
    int cx = bid % BEVW;
    int cy0 = (bid / BEVW) << 6;
    int tid = threadIdx.x;

    int cell_l = tid >> 3;
    int chq = (tid & 7) << 4;
    int cy = cy0 + cell_l;
    float4 v0 = make_float4(0.f,0.f,0.f,0.f), v1 = v0, v2 = v0, v3 = v0;
    if (cy < BEVH) {
        int ai = idx[cy*BEVW + cx] - 1;
        if (ai >= 0) {
            const float4* src = (const float4*)(x19c + (size_t)ai*128 + chq);
            v0 = src[0]; v1 = src[1]; v2 = src[2]; v3 = src[3];
        }
    }
    float* d = XT + chq*65 + cell_l;
    d[0*65]=v0.x;  d[1*65]=v0.y;  d[2*65]=v0.z;  d[3*65]=v0.w;
    d[4*65]=v1.x;  d[5*65]=v1.y;  d[6*65]=v1.z;  d[7*65]=v1.w;
    d[8*65]=v2.x;  d[9*65]=v2.y;  d[10*65]=v2.z; d[11*65]=v2.w;
    d[12*65]=v3.x; d[13*65]=v3.y; d[14*65]=v3.z; d[15*65]=v3.w;
    __syncthreads();

    int wv2 = tid >> 6, lane = tid & 63;
    int cyw = cy0 + lane;
    if (cyw < BEVH) {
        float* op = out + cx*BEVH + cyw;
#pragma unroll
        for (int k = 0; k < 16; k++) {
            int c = (wv2 << 4) + k;
            op[(size_t)c*NCELL] = XT[c*65 + lane];
        }
    }
}

extern "C" void kernel_launch(void* const* d_in, const int* in_sizes, int n_in,
                              void* d_out, int out_size, void* d_ws, size_t ws_size,
                              hipStream_t stream) {
    const float* features = (const float*)d_in[0];
    const int*   coors    = (const int*)d_in[1];
    const int*   num_vox  = (const int*)d_in[2];
    const float* vfe1_W   = (const float*)d_in[3];
    const float* vfe1_bn  = (const float*)d_in[4];
    const float* vfe2_W   = (const float*)d_in[5];
    const float* vfe2_bn  = (const float*)d_in[6];
    const float* vfe3_W   = (const float*)d_in[7];
    const float* vfe3_bn  = (const float*)d_in[8];
    const float* vfe4_W   = (const float*)d_in[9];
    const float* vfe4_bn  = (const float*)d_in[10];
    const float* bfe1_W   = (const float*)d_in[11];
    const float* bfe1_bn  = (const float*)d_in[12];
    const float* bfe2_W   = (const float*)d_in[13];
    const float* bfe2_bn  = (const float*)d_in[14];
    const float* bfe3_W   = (const float*)d_in[15];
    const float* bfe3_bn  = (const float*)d_in[16];
    float* out = (float*)d_out;

    char* ws = (char*)d_ws;
    int*    nact      = (int*)ws;                       // zeroed
    int*    cnt       = (int*)(ws + 256);               // zeroed
    int*    idx       = (int*)(ws + 857344);            // zeroed (aidx+1 encoding)
    int*    list      = (int*)(ws + 1714432);
    float*  voxelwise = (float*)(ws + 15427840);
    int*    act       = (int*)(ws + 25667840);
    float*  x17g      = (float*)(ws + 25827840);
    float*  fold      = (float*)(ws + 46307840);
    ushort* w4fh      = (ushort*)(ws + 46312512);
    ushort* w4fl      = (ushort*)(ws + 46320704);
    ushort* w3fh      = (ushort*)(ws + 46328896);
    ushort* w3fl      = (ushort*)(ws + 46337088);

    (void)hipMemsetAsync(ws, 0, 1714432, stream);   // nact + cnt + idx in one shot

    setup_kernel<<<1, 256, 0, stream>>>(vfe1_bn, vfe2_bn, vfe3_bn, vfe4_bn,
                                        bfe1_bn, bfe2_bn, bfe3_bn, vfe4_W, vfe3_W,
                                        fold, w4fh, w4fl, w3fh, w3fl);
    vfe_kernel<<<NVOX/2, 64, 0, stream>>>(features, coors, num_vox,
                                          vfe1_W, vfe2_W, w3fh, w3fl, w4fh, w4fl, fold,
                                          voxelwise, cnt, list, nact, act);
    bfe_front<<<NVOX/4, 256, 0, stream>>>(nact, act, cnt, list, voxelwise,
                                          bfe1_W, bfe2_W, fold, x17g, idx);
    bfe3_fused<<<(NVOX+63)/64, 512, 0, stream>>>(nact, bfe3_W, fold, x17g);
    bev_write<<<BEVW*8, 512, 0, stream>>>(idx, x17g, out);
}